// Round 1
// baseline (1572.159 us; speedup 1.0000x reference)
//
#include <hip/hip_runtime.h>
#include <math.h>

// N = 65536 nodes, E = 524288 edges, HID = 128, 128 graphs x 512 nodes
// fp32 throughout: absmax threshold ~9.8e-8 forbids bf16 MFMA.
// ROUND 1: persistent mega-kernel. Prior session measured ~10us/dispatch
// boundary as the biggest non-floor bucket (8 boundaries ~ 80us of 392.8us).
// All graph/GEMM/aggregate phases fused into ONE 768-block kernel with a
// monotonic-counter grid barrier (plain launch -> no cooperative-capture
// risk). 768 blocks = 3/CU exactly (LDS 50.8KB, launch_bounds(256,3) caps
// VGPR so 3 blocks/CU always fit -> no stranded-block deadlock).
// Dispatches: 9 -> 3 (memset[cnt+bar], mega, topk).

#define SLOTS 48
#define NBLK 768
#define ASTRIDE 257
#define WSTRIDE 140

static __device__ __forceinline__ float4 f4add(float4 a, float4 b) {
    return make_float4(a.x + b.x, a.y + b.y, a.z + b.z, a.w + b.w);
}
static __device__ __forceinline__ float4 f4fma(float s, float4 a, float4 acc) {
    return make_float4(fmaf(s, a.x, acc.x), fmaf(s, a.y, acc.y),
                       fmaf(s, a.z, acc.z), fmaf(s, a.w, acc.w));
}

// ---- grid barrier: monotonic counter, agent-scope fences (wbl2/inv) ----
// Release: __syncthreads drains vmcnt -> block stores sit in local XCD L2;
// leader __threadfence() writes back L2 before the arrive is visible.
// Acquire: after release, every thread fences (invalidate) before reading
// other XCDs' data. Counter only grows -> late spinners can't miss a phase.
static __device__ __forceinline__ void gridbar(int* bar, int expected) {
    __syncthreads();
    if (threadIdx.x == 0) {
        __threadfence();
        __hip_atomic_fetch_add(bar, 1, __ATOMIC_RELEASE, __HIP_MEMORY_SCOPE_AGENT);
        while (__hip_atomic_load(bar, __ATOMIC_ACQUIRE, __HIP_MEMORY_SCOPE_AGENT) < expected)
            __builtin_amdgcn_s_sleep(8);
    }
    __syncthreads();
    __threadfence();
}

// ---- weight fold: row r of [embW; embb] @ W0 -> W01/b01 (verbatim) ----
static __device__ __forceinline__ void fold_row(
    const float* __restrict__ embW, const float* __restrict__ embb,
    const float* __restrict__ W0, float* __restrict__ W01,
    float* __restrict__ b01, float* smem)
{
    float* rs   = smem;        // 128 floats
    float* part = smem + 128;  // 256 floats
    const int r = blockIdx.x;  // 0..128; r==128 -> bias row
    const int t = threadIdx.x;
    const int c = t & 127, q = t >> 7;
    if (t < 128) rs[t] = (r < 128) ? embW[r * 128 + t] : embb[t];
    __syncthreads();
    float s = 0.f;
    const int k0 = q * 64;
#pragma unroll 8
    for (int k = k0; k < k0 + 64; k++) s = fmaf(rs[k], W0[k * 128 + c], s);
    part[t] = s;
    __syncthreads();
    if (q == 0) {
        float v = part[c] + part[c + 128];
        if (r < 128) W01[r * 128 + c] = v;
        else         b01[c] = v;
    }
    __syncthreads();
}

// ---- GEMM tile: rows [bid*128, bid*128+128) of [n,128]@[128,128] --------
// Round-5/8 proven structure: 8x8 microtile, single-buffered LDS, register
// prefetch, ASTRIDE=257 / WSTRIDE=140 + col swizzle. Body verbatim.
static __device__ __forceinline__ void gemm_tile(
    const float* __restrict__ A, const float* __restrict__ W,
    const float* __restrict__ bias, const int* __restrict__ rowdeg,
    float* __restrict__ out, float* __restrict__ As, float* __restrict__ Ws)
{
    const int tid  = threadIdx.x;
    const int rb   = blockIdx.x * 128;
    const int tc   = tid & 15;
    const int tr   = tid >> 4;
    const int colg = tc * 8;
    const int cswz = colg + ((colg >> 5) << 2);
    const int rowg = tr * 8;

    const int a_kq = tid & 7;
    const int a_m  = tid >> 3;
    const int w_c  = (tid & 31) * 4;
    const int w_cs = w_c + ((w_c >> 5) << 2);
    const int w_k  = tid >> 5;

    float acc[8][8];
#pragma unroll
    for (int i = 0; i < 8; i++)
#pragma unroll
        for (int j = 0; j < 8; j++) acc[i][j] = 0.f;

    float4 areg[4], wreg[4];
#pragma unroll
    for (int t = 0; t < 4; t++)
        areg[t] = *(const float4*)&A[(size_t)(rb + t * 32 + a_m) * 128 + a_kq * 4];
#pragma unroll
    for (int t = 0; t < 4; t++)
        wreg[t] = *(const float4*)&W[(size_t)(t * 8 + w_k) * 128 + w_c];

#pragma unroll 1
    for (int k0 = 0; k0 < 128; k0 += 32) {
#pragma unroll
        for (int t = 0; t < 4; t++) {
            const int m = t * 32 + a_m;
            const float4 av = areg[t];
            As[(a_kq * 4 + 0) * ASTRIDE + m] = av.x;
            As[(a_kq * 4 + 1) * ASTRIDE + m] = av.y;
            As[(a_kq * 4 + 2) * ASTRIDE + m] = av.z;
            As[(a_kq * 4 + 3) * ASTRIDE + m] = av.w;
        }
#pragma unroll
        for (int t = 0; t < 4; t++)
            *(float4*)&Ws[(t * 8 + w_k) * WSTRIDE + w_cs] = wreg[t];
        __syncthreads();
        if (k0 < 96) {
#pragma unroll
            for (int t = 0; t < 4; t++)
                areg[t] = *(const float4*)&A[(size_t)(rb + t * 32 + a_m) * 128 + k0 + 32 + a_kq * 4];
#pragma unroll
            for (int t = 0; t < 4; t++)
                wreg[t] = *(const float4*)&W[(size_t)(k0 + 32 + t * 8 + w_k) * 128 + w_c];
        }
#pragma unroll 8
        for (int kk = 0; kk < 32; kk++) {
            float4 a0 = *(const float4*)&As[kk * ASTRIDE + rowg];
            float4 a1 = *(const float4*)&As[kk * ASTRIDE + rowg + 4];
            float4 b0 = *(const float4*)&Ws[kk * WSTRIDE + cswz];
            float4 b1 = *(const float4*)&Ws[kk * WSTRIDE + cswz + 4];
            float av[8] = {a0.x, a0.y, a0.z, a0.w, a1.x, a1.y, a1.z, a1.w};
            float bv[8] = {b0.x, b0.y, b0.z, b0.w, b1.x, b1.y, b1.z, b1.w};
#pragma unroll
            for (int i = 0; i < 8; i++)
#pragma unroll
                for (int j = 0; j < 8; j++) acc[i][j] = fmaf(av[i], bv[j], acc[i][j]);
        }
        __syncthreads();
    }

    float4 bb0 = make_float4(0.f, 0.f, 0.f, 0.f), bb1 = bb0;
    if (bias) {
        bb0 = *(const float4*)&bias[colg];
        bb1 = *(const float4*)&bias[colg + 4];
    }
#pragma unroll
    for (int i = 0; i < 8; i++) {
        const int row  = rb + rowg + i;
        const float sc = rowdeg ? rsqrtf((float)(rowdeg[row] + 1)) : 1.f;
        float4 o0, o1;
        o0.x = (acc[i][0] + bb0.x) * sc;  o0.y = (acc[i][1] + bb0.y) * sc;
        o0.z = (acc[i][2] + bb0.z) * sc;  o0.w = (acc[i][3] + bb0.w) * sc;
        o1.x = (acc[i][4] + bb1.x) * sc;  o1.y = (acc[i][5] + bb1.y) * sc;
        o1.z = (acc[i][6] + bb1.z) * sc;  o1.w = (acc[i][7] + bb1.w) * sc;
        *(float4*)&out[(size_t)row * 128 + colg]     = o0;
        *(float4*)&out[(size_t)row * 128 + colg + 4] = o1;
    }
}

// ---- aggregation phase: grid-stride over 8-node groups (body verbatim) --
static __device__ __forceinline__ void agg_phase(
    const float* __restrict__ hs, const int* __restrict__ csr_pad,
    const int* __restrict__ cnt, const float* __restrict__ bias,
    float* __restrict__ hout, const float* __restrict__ pool_p,
    float* __restrict__ scores, int n)
{
    const int grp  = threadIdx.x >> 5;
    const int lane = threadIdx.x & 31;
    const float4* __restrict__ hv = (const float4*)hs;
    const float4 bb = ((const float4*)bias)[lane];
    const int ngrp = n >> 3;

    for (int v = blockIdx.x; v < ngrp; v += NBLK) {
        const int node = v * 8 + grp;
        const int deg  = cnt[node];
        const int e0   = node * SLOTS;

        int   ix[16];
        float mk[16];
#pragma unroll
        for (int j = 0; j < 16; j++) {
            const int raw = csr_pad[e0 + j];     // always in-bounds memory
            const bool vv = j < deg;
            ix[j] = vv ? raw : node;             // clamp poison before use
            mk[j] = vv ? 1.f : 0.f;
        }

        float4 self = hv[(size_t)node * 32 + lane];
        float4 r[16];
#pragma unroll
        for (int j = 0; j < 16; j++)
            r[j] = hv[(size_t)ix[j] * 32 + lane];
        asm volatile("" ::: "memory");  // keep the 16 loads in flight

        float4 a0 = self;
        float4 a1 = make_float4(0.f, 0.f, 0.f, 0.f);
        float4 a2 = a1, a3 = a1;
#pragma unroll
        for (int j = 0; j < 16; j += 4) {
            a0 = f4fma(mk[j + 0], r[j + 0], a0);
            a1 = f4fma(mk[j + 1], r[j + 1], a1);
            a2 = f4fma(mk[j + 2], r[j + 2], a2);
            a3 = f4fma(mk[j + 3], r[j + 3], a3);
        }
        const int dcap = deg < SLOTS ? deg : SLOTS;
        for (int j = 16; j < dcap; j++) {  // rare tail (deg > 16)
            a1 = f4add(a1, hv[(size_t)csr_pad[e0 + j] * 32 + lane]);
        }

        float4 s = f4add(f4add(a0, a1), f4add(a2, a3));
        const float dv = rsqrtf((float)(deg + 1));
        float4 o;
        o.x = fmaxf(fmaf(s.x, dv, bb.x), 0.f);
        o.y = fmaxf(fmaf(s.y, dv, bb.y), 0.f);
        o.z = fmaxf(fmaf(s.z, dv, bb.z), 0.f);
        o.w = fmaxf(fmaf(s.w, dv, bb.w), 0.f);
        ((float4*)hout)[(size_t)node * 32 + lane] = o;

        if (scores) {  // wave-uniform branch (fused pooling score)
            float4 pv = ((const float4*)pool_p)[lane];
            float d  = o.x * pv.x + o.y * pv.y + o.z * pv.z + o.w * pv.w;
            float nn = pv.x * pv.x + pv.y * pv.y + pv.z * pv.z + pv.w * pv.w;
#pragma unroll
            for (int off = 16; off > 0; off >>= 1) {
                d  += __shfl_xor(d, off);
                nn += __shfl_xor(nn, off);
            }
            if (lane == 0) scores[node] = d * rsqrtf(nn);
        }
    }
}

// =========================== persistent mega-kernel =========================
// P0: edge scatter (all blocks) + weight fold (blocks 0..128)      | bar 1
// P1: gemm0 x@W01 (blocks 0..511)                                  | bar 2
// P2/3/4: aggregate l / gemm l+1 alternating                       | bar 3..6
// P4 tail: aggregate l=2 + pooling scores, then kernel end.
__global__ __launch_bounds__(256, 3) void mega(
    const int* __restrict__ src, const int* __restrict__ dst,
    int* __restrict__ cnt, int* __restrict__ csr_pad, int* __restrict__ bar,
    const float* __restrict__ x,
    const float* __restrict__ embW, const float* __restrict__ embb,
    const float* __restrict__ gcnW, const float* __restrict__ gcnb,
    float* __restrict__ W01, float* __restrict__ b01,
    float* __restrict__ hs, float* __restrict__ h,
    const float* __restrict__ poolp, float* __restrict__ scores,
    int E, int n)
{
    __shared__ float smem[32 * ASTRIDE + 32 * WSTRIDE];  // 50816 B
    float* As = smem;
    float* Ws = smem + 32 * ASTRIDE;

    // ---- P0: CSR scatter (grid-stride; uniform trip count per block) ----
    for (int e = blockIdx.x * 256 + threadIdx.x; e < E; e += NBLK * 256) {
        int d = dst[e];
        int r = atomicAdd(&cnt[d], 1);
        if (r < SLOTS) csr_pad[d * SLOTS + r] = src[e];
    }
    if (blockIdx.x < 129) fold_row(embW, embb, gcnW, W01, b01, smem);
    gridbar(bar, 1 * NBLK);

    // ---- P1: layer-0 GEMM (folded embedding) ----
    if (blockIdx.x < 512) gemm_tile(x, W01, b01, cnt, hs, As, Ws);
    gridbar(bar, 2 * NBLK);

    // ---- P2..P4: aggregate l, then gemm l+1 ----
    for (int l = 0; l < 3; l++) {
        agg_phase(hs, csr_pad, cnt, gcnb + (size_t)l * 128, h,
                  poolp, (l == 2) ? scores : nullptr, n);
        if (l < 2) {
            gridbar(bar, (3 + 2 * l) * NBLK);
            if (blockIdx.x < 512)
                gemm_tile(h, gcnW + (size_t)(l + 1) * 128 * 128,
                          nullptr, cnt, hs, As, Ws);
            gridbar(bar, (4 + 2 * l) * NBLK);
        }
    }
}

// ==================== TopK pool (k=256 of 512) + MLP head ===================
__global__ __launch_bounds__(512) void topk_mlp(
    const float* __restrict__ scores, const float* __restrict__ h,
    const float* __restrict__ fc1W, const float* __restrict__ fc1b,
    const float* __restrict__ fc2W, const float* __restrict__ fc2b,
    const float* __restrict__ fc3W, const float* __restrict__ fc3b,
    float* __restrict__ out)
{
    __shared__ float s[512];
    __shared__ int   sel[256];
    __shared__ float w[256];
    __shared__ float4 red[512];
    __shared__ float pld[128];
    __shared__ float z1[128];
    __shared__ float z2[64];
    const int g = blockIdx.x;
    const int i = threadIdx.x;
    s[i] = scores[g * 512 + i];
    __syncthreads();
    float si = s[i];
    int rank = 0;
    for (int j = 0; j < 512; j++) {
        float sj = s[j];
        rank += (sj > si) || (sj == si && j < i);
    }
    if (rank < 256) {
        sel[rank] = i;
        w[rank]   = tanhf(si) * (1.f / 256.f);
    }
    __syncthreads();
    const int c   = (i & 31) * 4;
    const int grp = i >> 5;
    float4 acc = make_float4(0.f, 0.f, 0.f, 0.f);
    for (int t = grp; t < 256; t += 16) {
        float wt  = w[t];
        int   idx = sel[t];
        float4 r = *(const float4*)&h[((size_t)g * 512 + idx) * 128 + c];
        acc = f4fma(wt, r, acc);
    }
    red[i] = acc;
    __syncthreads();
    if (i < 256) red[i] = f4add(red[i], red[i + 256]);
    __syncthreads();
    if (i < 128) red[i] = f4add(red[i], red[i + 128]);
    __syncthreads();
    if (i < 64) red[i] = f4add(red[i], red[i + 64]);
    __syncthreads();
    if (i < 32) {
        float4 v = f4add(red[i], red[i + 32]);
        *(float4*)&pld[i * 4] = v;
    }
    __syncthreads();
    if (i < 128) {
        float a = fc1b[i];
        for (int k = 0; k < 128; k++) a += pld[k] * fc1W[k * 128 + i];
        z1[i] = fmaxf(a, 0.f);
    }
    __syncthreads();
    if (i < 64) {
        float b = fc2b[i];
        for (int k = 0; k < 128; k++) b += z1[k] * fc2W[k * 64 + i];
        z2[i] = fmaxf(b, 0.f);
    }
    __syncthreads();
    if (i < 10) {
        float o = fc3b[i];
        for (int k = 0; k < 64; k++) o += z2[k] * fc3W[k * 10 + i];
        out[g * 10 + i] = o;
    }
}

// ============================ Launcher ======================================
extern "C" void kernel_launch(void* const* d_in, const int* in_sizes, int n_in,
                              void* d_out, int out_size, void* d_ws, size_t ws_size,
                              hipStream_t stream)
{
    const float* x     = (const float*)d_in[0];
    const int*   eidx  = (const int*)d_in[1];
    const float* embW  = (const float*)d_in[3];
    const float* embb  = (const float*)d_in[4];
    const float* gcnW  = (const float*)d_in[5];
    const float* gcnb  = (const float*)d_in[6];
    const float* poolp = (const float*)d_in[7];
    const float* fc1W  = (const float*)d_in[8];
    const float* fc1b  = (const float*)d_in[9];
    const float* fc2W  = (const float*)d_in[10];
    const float* fc2b  = (const float*)d_in[11];
    const float* fc3W  = (const float*)d_in[12];
    const float* fc3b  = (const float*)d_in[13];
    float* out = (float*)d_out;

    const int n = in_sizes[0] / 128;   // 65536
    const int E = in_sizes[1] / 2;     // 524288
    const int G = n / 512;             // 128

    const int* src = eidx;
    const int* dst = eidx + E;

    char* ws = (char*)d_ws;
    size_t off = 0;
    auto carve = [&](size_t bytes) {
        void* p = ws + off;
        off += (bytes + 255) & ~(size_t)255;
        return p;
    };
    float* h       = (float*)carve((size_t)n * 128 * 4);
    float* hs      = (float*)carve((size_t)n * 128 * 4);
    int*   cnt     = (int*)carve((size_t)(n + 64) * 4);  // +bar tail
    int*   csr_pad = (int*)carve((size_t)n * SLOTS * 4);
    float* scores  = (float*)carve((size_t)n * 4);
    float* W01     = (float*)carve(128 * 128 * 4);
    float* b01     = (float*)carve(128 * 4);
    (void)ws_size;

    int* bar = cnt + n;

    // zero degree counters + grid barrier in one memset
    hipMemsetAsync(cnt, 0, (size_t)(n + 64) * 4, stream);

    mega<<<NBLK, 256, 0, stream>>>(src, dst, cnt, csr_pad, bar, x,
                                   embW, embb, gcnW, gcnb, W01, b01,
                                   hs, h, poolp, scores, E, n);

    topk_mlp<<<G, 512, 0, stream>>>(scores, h, fc1W, fc1b, fc2W, fc2b,
                                    fc3W, fc3b, out);
}

// Round 2
// 886.694 us; speedup vs baseline: 1.7731x; 1.7731x over previous
//
#include <hip/hip_runtime.h>
#include <math.h>

// N = 65536 nodes, E = 524288 edges, HID = 128, 128 graphs x 512 nodes
// fp32 throughout: absmax threshold ~9.8e-8 forbids bf16 MFMA.
// ROUND 2: barrier rework. Round-1 mega (1500us, VALUBusy 5.4%, FETCH 477MB)
// showed the grid barrier was ~200us each: ACQUIRE-agent polling emits
// buffer_inv per poll -> 768 spinners continuously invalidate L1/L2 of XCDs
// whose other blocks are still computing (also +250MB refill traffic), and
// arrive counter was a 768-way RMW+read ping-pong line.
// Fix: (1) write-once release flag, polled with RELAXED-agent loads (no
// cache-maintenance side effects; agent atomics operate at the coherence
// point so progress is observed); (2) hierarchical arrive: 32 group lines
// x 24 RMWs, nobody polls arrive lines; (3) single acquire fence per
// barrier after spin exit (same semantics as the round-1 version that
// PASSED correctness).
// Side changes (analytically safe): ASTRIDE 257->129 (both ==1 mod 32 ->
// identical bank mapping, LDS 51.2->35KB) and amdgpu_waves_per_eu(3,3) so
// regalloc uses the full 170-VGPR budget (r1 got 80 VGPRs vs ~130 live in
// GEMM -> spills).

#define SLOTS 48
#define NBLK 768
#define GRPS 32
#define GSIZE (NBLK / GRPS)      // 24
#define ASTRIDE 129
#define WSTRIDE 140

static __device__ __forceinline__ float4 f4add(float4 a, float4 b) {
    return make_float4(a.x + b.x, a.y + b.y, a.z + b.z, a.w + b.w);
}
static __device__ __forceinline__ float4 f4fma(float s, float4 a, float4 acc) {
    return make_float4(fmaf(s, a.x, acc.x), fmaf(s, a.y, acc.y),
                       fmaf(s, a.z, acc.z), fmaf(s, a.w, acc.w));
}

// ---- grid barrier: hierarchical arrive + write-once release flag --------
// barmem layout (ints): arrive[GRPS] at 128B stride, then g2, then rel.
// Release path: block's stores are in its XCD L2 after __syncthreads (the
// compiler drains vmcnt before s_barrier); the RELEASE-agent fetch_add does
// the L2 writeback. Arrive counters are monotonic across phases; the
// arriver seeing old == phase*GSIZE-1 is the group leader; the group
// leader seeing old == phase*GRPS-1 on g2 publishes the phase number to
// `rel` (one store). Everyone polls `rel` with RELAXED loads + s_sleep
// (no buffer_inv in the spin). Acquire: one __threadfence after exit.
static __device__ __forceinline__ void gridbar(int* barmem, int phase) {
    __syncthreads();
    if (threadIdx.x == 0) {
        int* arrive = barmem + (blockIdx.x & (GRPS - 1)) * 32;
        int* g2     = barmem + GRPS * 32;
        int* rel    = barmem + GRPS * 32 + 32;
        int old = __hip_atomic_fetch_add(arrive, 1, __ATOMIC_RELEASE,
                                         __HIP_MEMORY_SCOPE_AGENT);
        if (old == phase * GSIZE - 1) {
            int o2 = __hip_atomic_fetch_add(g2, 1, __ATOMIC_RELAXED,
                                            __HIP_MEMORY_SCOPE_AGENT);
            if (o2 == phase * GRPS - 1)
                __hip_atomic_store(rel, phase, __ATOMIC_RELEASE,
                                   __HIP_MEMORY_SCOPE_AGENT);
        }
        while (__hip_atomic_load(rel, __ATOMIC_RELAXED,
                                 __HIP_MEMORY_SCOPE_AGENT) < phase)
            __builtin_amdgcn_s_sleep(16);
    }
    __syncthreads();
    __threadfence();  // acquire: drop stale L1/L2 lines once, then compute
}

// ---- weight fold: row r of [embW; embb] @ W0 -> W01/b01 (verbatim) ----
static __device__ __forceinline__ void fold_row(
    const float* __restrict__ embW, const float* __restrict__ embb,
    const float* __restrict__ W0, float* __restrict__ W01,
    float* __restrict__ b01, float* smem)
{
    float* rs   = smem;        // 128 floats
    float* part = smem + 128;  // 256 floats
    const int r = blockIdx.x;  // 0..128; r==128 -> bias row
    const int t = threadIdx.x;
    const int c = t & 127, q = t >> 7;
    if (t < 128) rs[t] = (r < 128) ? embW[r * 128 + t] : embb[t];
    __syncthreads();
    float s = 0.f;
    const int k0 = q * 64;
#pragma unroll 8
    for (int k = k0; k < k0 + 64; k++) s = fmaf(rs[k], W0[k * 128 + c], s);
    part[t] = s;
    __syncthreads();
    if (q == 0) {
        float v = part[c] + part[c + 128];
        if (r < 128) W01[r * 128 + c] = v;
        else         b01[c] = v;
    }
    __syncthreads();
}

// ---- GEMM tile: rows [bid*128, bid*128+128) of [n,128]@[128,128] --------
// Round-5/8 proven structure: 8x8 microtile, single-buffered LDS, register
// prefetch. ASTRIDE=129 (==1 mod 32, same bank rotation as the proven 257,
// half the LDS). WSTRIDE=140 + col swizzle c->c+4*(c>>5).
static __device__ __forceinline__ void gemm_tile(
    const float* __restrict__ A, const float* __restrict__ W,
    const float* __restrict__ bias, const int* __restrict__ rowdeg,
    float* __restrict__ out, float* __restrict__ As, float* __restrict__ Ws)
{
    const int tid  = threadIdx.x;
    const int rb   = blockIdx.x * 128;
    const int tc   = tid & 15;
    const int tr   = tid >> 4;
    const int colg = tc * 8;
    const int cswz = colg + ((colg >> 5) << 2);
    const int rowg = tr * 8;

    const int a_kq = tid & 7;
    const int a_m  = tid >> 3;
    const int w_c  = (tid & 31) * 4;
    const int w_cs = w_c + ((w_c >> 5) << 2);
    const int w_k  = tid >> 5;

    float acc[8][8];
#pragma unroll
    for (int i = 0; i < 8; i++)
#pragma unroll
        for (int j = 0; j < 8; j++) acc[i][j] = 0.f;

    float4 areg[4], wreg[4];
#pragma unroll
    for (int t = 0; t < 4; t++)
        areg[t] = *(const float4*)&A[(size_t)(rb + t * 32 + a_m) * 128 + a_kq * 4];
#pragma unroll
    for (int t = 0; t < 4; t++)
        wreg[t] = *(const float4*)&W[(size_t)(t * 8 + w_k) * 128 + w_c];

#pragma unroll 1
    for (int k0 = 0; k0 < 128; k0 += 32) {
#pragma unroll
        for (int t = 0; t < 4; t++) {
            const int m = t * 32 + a_m;
            const float4 av = areg[t];
            As[(a_kq * 4 + 0) * ASTRIDE + m] = av.x;
            As[(a_kq * 4 + 1) * ASTRIDE + m] = av.y;
            As[(a_kq * 4 + 2) * ASTRIDE + m] = av.z;
            As[(a_kq * 4 + 3) * ASTRIDE + m] = av.w;
        }
#pragma unroll
        for (int t = 0; t < 4; t++)
            *(float4*)&Ws[(t * 8 + w_k) * WSTRIDE + w_cs] = wreg[t];
        __syncthreads();
        if (k0 < 96) {
#pragma unroll
            for (int t = 0; t < 4; t++)
                areg[t] = *(const float4*)&A[(size_t)(rb + t * 32 + a_m) * 128 + k0 + 32 + a_kq * 4];
#pragma unroll
            for (int t = 0; t < 4; t++)
                wreg[t] = *(const float4*)&W[(size_t)(k0 + 32 + t * 8 + w_k) * 128 + w_c];
        }
#pragma unroll 8
        for (int kk = 0; kk < 32; kk++) {
            float4 a0 = *(const float4*)&As[kk * ASTRIDE + rowg];
            float4 a1 = *(const float4*)&As[kk * ASTRIDE + rowg + 4];
            float4 b0 = *(const float4*)&Ws[kk * WSTRIDE + cswz];
            float4 b1 = *(const float4*)&Ws[kk * WSTRIDE + cswz + 4];
            float av[8] = {a0.x, a0.y, a0.z, a0.w, a1.x, a1.y, a1.z, a1.w};
            float bv[8] = {b0.x, b0.y, b0.z, b0.w, b1.x, b1.y, b1.z, b1.w};
#pragma unroll
            for (int i = 0; i < 8; i++)
#pragma unroll
                for (int j = 0; j < 8; j++) acc[i][j] = fmaf(av[i], bv[j], acc[i][j]);
        }
        __syncthreads();
    }

    float4 bb0 = make_float4(0.f, 0.f, 0.f, 0.f), bb1 = bb0;
    if (bias) {
        bb0 = *(const float4*)&bias[colg];
        bb1 = *(const float4*)&bias[colg + 4];
    }
#pragma unroll
    for (int i = 0; i < 8; i++) {
        const int row  = rb + rowg + i;
        const float sc = rowdeg ? rsqrtf((float)(rowdeg[row] + 1)) : 1.f;
        float4 o0, o1;
        o0.x = (acc[i][0] + bb0.x) * sc;  o0.y = (acc[i][1] + bb0.y) * sc;
        o0.z = (acc[i][2] + bb0.z) * sc;  o0.w = (acc[i][3] + bb0.w) * sc;
        o1.x = (acc[i][4] + bb1.x) * sc;  o1.y = (acc[i][5] + bb1.y) * sc;
        o1.z = (acc[i][6] + bb1.z) * sc;  o1.w = (acc[i][7] + bb1.w) * sc;
        *(float4*)&out[(size_t)row * 128 + colg]     = o0;
        *(float4*)&out[(size_t)row * 128 + colg + 4] = o1;
    }
}

// ---- aggregation phase: grid-stride over 8-node groups (body verbatim) --
static __device__ __forceinline__ void agg_phase(
    const float* __restrict__ hs, const int* __restrict__ csr_pad,
    const int* __restrict__ cnt, const float* __restrict__ bias,
    float* __restrict__ hout, const float* __restrict__ pool_p,
    float* __restrict__ scores, int n)
{
    const int grp  = threadIdx.x >> 5;
    const int lane = threadIdx.x & 31;
    const float4* __restrict__ hv = (const float4*)hs;
    const float4 bb = ((const float4*)bias)[lane];
    const int ngrp = n >> 3;

    for (int v = blockIdx.x; v < ngrp; v += NBLK) {
        const int node = v * 8 + grp;
        const int deg  = cnt[node];
        const int e0   = node * SLOTS;

        int   ix[16];
        float mk[16];
#pragma unroll
        for (int j = 0; j < 16; j++) {
            const int raw = csr_pad[e0 + j];     // always in-bounds memory
            const bool vv = j < deg;
            ix[j] = vv ? raw : node;             // clamp poison before use
            mk[j] = vv ? 1.f : 0.f;
        }

        float4 self = hv[(size_t)node * 32 + lane];
        float4 r[16];
#pragma unroll
        for (int j = 0; j < 16; j++)
            r[j] = hv[(size_t)ix[j] * 32 + lane];
        asm volatile("" ::: "memory");  // keep the 16 loads in flight

        float4 a0 = self;
        float4 a1 = make_float4(0.f, 0.f, 0.f, 0.f);
        float4 a2 = a1, a3 = a1;
#pragma unroll
        for (int j = 0; j < 16; j += 4) {
            a0 = f4fma(mk[j + 0], r[j + 0], a0);
            a1 = f4fma(mk[j + 1], r[j + 1], a1);
            a2 = f4fma(mk[j + 2], r[j + 2], a2);
            a3 = f4fma(mk[j + 3], r[j + 3], a3);
        }
        const int dcap = deg < SLOTS ? deg : SLOTS;
        for (int j = 16; j < dcap; j++) {  // rare tail (deg > 16)
            a1 = f4add(a1, hv[(size_t)csr_pad[e0 + j] * 32 + lane]);
        }

        float4 s = f4add(f4add(a0, a1), f4add(a2, a3));
        const float dv = rsqrtf((float)(deg + 1));
        float4 o;
        o.x = fmaxf(fmaf(s.x, dv, bb.x), 0.f);
        o.y = fmaxf(fmaf(s.y, dv, bb.y), 0.f);
        o.z = fmaxf(fmaf(s.z, dv, bb.z), 0.f);
        o.w = fmaxf(fmaf(s.w, dv, bb.w), 0.f);
        ((float4*)hout)[(size_t)node * 32 + lane] = o;

        if (scores) {  // wave-uniform branch (fused pooling score)
            float4 pv = ((const float4*)pool_p)[lane];
            float d  = o.x * pv.x + o.y * pv.y + o.z * pv.z + o.w * pv.w;
            float nn = pv.x * pv.x + pv.y * pv.y + pv.z * pv.z + pv.w * pv.w;
#pragma unroll
            for (int off = 16; off > 0; off >>= 1) {
                d  += __shfl_xor(d, off);
                nn += __shfl_xor(nn, off);
            }
            if (lane == 0) scores[node] = d * rsqrtf(nn);
        }
    }
}

// =========================== persistent mega-kernel =========================
// P0: edge scatter (all blocks) + weight fold (blocks 0..128)      | bar 1
// P1: gemm0 x@W01 (blocks 0..511)                                  | bar 2
// P2..: aggregate l / gemm l+1 alternating                         | bar 3..6
// tail: aggregate l=2 + pooling scores, then kernel end.
__global__ void __launch_bounds__(256)
__attribute__((amdgpu_waves_per_eu(3, 3)))
mega(
    const int* __restrict__ src, const int* __restrict__ dst,
    int* __restrict__ cnt, int* __restrict__ csr_pad, int* __restrict__ bar,
    const float* __restrict__ x,
    const float* __restrict__ embW, const float* __restrict__ embb,
    const float* __restrict__ gcnW, const float* __restrict__ gcnb,
    float* __restrict__ W01, float* __restrict__ b01,
    float* __restrict__ hs, float* __restrict__ h,
    const float* __restrict__ poolp, float* __restrict__ scores,
    int E, int n)
{
    __shared__ float smem[32 * ASTRIDE + 32 * WSTRIDE];  // 34432 B
    float* As = smem;
    float* Ws = smem + 32 * ASTRIDE;

    // ---- P0: CSR scatter (grid-stride) + weight fold ----
    for (int e = blockIdx.x * 256 + threadIdx.x; e < E; e += NBLK * 256) {
        int d = dst[e];
        int r = atomicAdd(&cnt[d], 1);
        if (r < SLOTS) csr_pad[d * SLOTS + r] = src[e];
    }
    if (blockIdx.x < 129) fold_row(embW, embb, gcnW, W01, b01, smem);
    gridbar(bar, 1);

    // ---- P1: layer-0 GEMM (folded embedding) ----
    if (blockIdx.x < 512) gemm_tile(x, W01, b01, cnt, hs, As, Ws);
    gridbar(bar, 2);

    // ---- P2..: aggregate l, then gemm l+1 ----
    for (int l = 0; l < 3; l++) {
        agg_phase(hs, csr_pad, cnt, gcnb + (size_t)l * 128, h,
                  poolp, (l == 2) ? scores : nullptr, n);
        if (l < 2) {
            gridbar(bar, 3 + 2 * l);
            if (blockIdx.x < 512)
                gemm_tile(h, gcnW + (size_t)(l + 1) * 128 * 128,
                          nullptr, cnt, hs, As, Ws);
            gridbar(bar, 4 + 2 * l);
        }
    }
}

// ==================== TopK pool (k=256 of 512) + MLP head ===================
__global__ __launch_bounds__(512) void topk_mlp(
    const float* __restrict__ scores, const float* __restrict__ h,
    const float* __restrict__ fc1W, const float* __restrict__ fc1b,
    const float* __restrict__ fc2W, const float* __restrict__ fc2b,
    const float* __restrict__ fc3W, const float* __restrict__ fc3b,
    float* __restrict__ out)
{
    __shared__ float s[512];
    __shared__ int   sel[256];
    __shared__ float w[256];
    __shared__ float4 red[512];
    __shared__ float pld[128];
    __shared__ float z1[128];
    __shared__ float z2[64];
    const int g = blockIdx.x;
    const int i = threadIdx.x;
    s[i] = scores[g * 512 + i];
    __syncthreads();
    float si = s[i];
    int rank = 0;
    for (int j = 0; j < 512; j++) {
        float sj = s[j];
        rank += (sj > si) || (sj == si && j < i);
    }
    if (rank < 256) {
        sel[rank] = i;
        w[rank]   = tanhf(si) * (1.f / 256.f);
    }
    __syncthreads();
    const int c   = (i & 31) * 4;
    const int grp = i >> 5;
    float4 acc = make_float4(0.f, 0.f, 0.f, 0.f);
    for (int t = grp; t < 256; t += 16) {
        float wt  = w[t];
        int   idx = sel[t];
        float4 r = *(const float4*)&h[((size_t)g * 512 + idx) * 128 + c];
        acc = f4fma(wt, r, acc);
    }
    red[i] = acc;
    __syncthreads();
    if (i < 256) red[i] = f4add(red[i], red[i + 256]);
    __syncthreads();
    if (i < 128) red[i] = f4add(red[i], red[i + 128]);
    __syncthreads();
    if (i < 64) red[i] = f4add(red[i], red[i + 64]);
    __syncthreads();
    if (i < 32) {
        float4 v = f4add(red[i], red[i + 32]);
        *(float4*)&pld[i * 4] = v;
    }
    __syncthreads();
    if (i < 128) {
        float a = fc1b[i];
        for (int k = 0; k < 128; k++) a += pld[k] * fc1W[k * 128 + i];
        z1[i] = fmaxf(a, 0.f);
    }
    __syncthreads();
    if (i < 64) {
        float b = fc2b[i];
        for (int k = 0; k < 128; k++) b += z1[k] * fc2W[k * 64 + i];
        z2[i] = fmaxf(b, 0.f);
    }
    __syncthreads();
    if (i < 10) {
        float o = fc3b[i];
        for (int k = 0; k < 64; k++) o += z2[k] * fc3W[k * 10 + i];
        out[g * 10 + i] = o;
    }
}

// ============================ Launcher ======================================
extern "C" void kernel_launch(void* const* d_in, const int* in_sizes, int n_in,
                              void* d_out, int out_size, void* d_ws, size_t ws_size,
                              hipStream_t stream)
{
    const float* x     = (const float*)d_in[0];
    const int*   eidx  = (const int*)d_in[1];
    const float* embW  = (const float*)d_in[3];
    const float* embb  = (const float*)d_in[4];
    const float* gcnW  = (const float*)d_in[5];
    const float* gcnb  = (const float*)d_in[6];
    const float* poolp = (const float*)d_in[7];
    const float* fc1W  = (const float*)d_in[8];
    const float* fc1b  = (const float*)d_in[9];
    const float* fc2W  = (const float*)d_in[10];
    const float* fc2b  = (const float*)d_in[11];
    const float* fc3W  = (const float*)d_in[12];
    const float* fc3b  = (const float*)d_in[13];
    float* out = (float*)d_out;

    const int n = in_sizes[0] / 128;   // 65536
    const int E = in_sizes[1] / 2;     // 524288
    const int G = n / 512;             // 128

    const int* src = eidx;
    const int* dst = eidx + E;

    char* ws = (char*)d_ws;
    size_t off = 0;
    auto carve = [&](size_t bytes) {
        void* p = ws + off;
        off += (bytes + 255) & ~(size_t)255;
        return p;
    };
    float* h       = (float*)carve((size_t)n * 128 * 4);
    float* hs      = (float*)carve((size_t)n * 128 * 4);
    int*   cnt     = (int*)carve((size_t)n * 4);          // 256-aligned size
    int*   bar     = (int*)carve(4608);                   // contiguous w/ cnt
    int*   csr_pad = (int*)carve((size_t)n * SLOTS * 4);
    float* scores  = (float*)carve((size_t)n * 4);
    float* W01     = (float*)carve(128 * 128 * 4);
    float* b01     = (float*)carve(128 * 4);
    (void)ws_size;

    // zero degree counters + barrier memory in one memset (contiguous)
    hipMemsetAsync(cnt, 0, (size_t)n * 4 + 4608, stream);

    mega<<<NBLK, 256, 0, stream>>>(src, dst, cnt, csr_pad, bar, x,
                                   embW, embb, gcnW, gcnb, W01, b01,
                                   hs, h, poolp, scores, E, n);

    topk_mlp<<<G, 512, 0, stream>>>(scores, h, fc1W, fc1b, fc2W, fc2b,
                                    fc3W, fc3b, out);
}

// Round 3
// 839.708 us; speedup vs baseline: 1.8723x; 1.0560x over previous
//
#include <hip/hip_runtime.h>
#include <math.h>

// N = 65536 nodes, E = 524288 edges, HID = 128, 128 graphs x 512 nodes
// fp32 throughout: absmax threshold ~9.8e-8 forbids bf16 MFMA.
// ROUND 3: occupancy + ILP + cheap barrier maintenance.
// r2 evidence: LDS_Block_Size stayed 51200 -> amdgpu_waves_per_eu(3,3) made
// the compiler PAD LDS to cap occupancy at 3 blocks/CU; VGPR 84 -> the 16
// in-flight float4 gathers (64 regs) were split into small batches.
// Fixes: (1) __launch_bounds__(256,4): VGPR<=128 hard cap, no LDS pad ->
// 4 blocks/CU, 1024 blocks = exact capacity (co-residency guaranteed).
// (2) zero-row gather: masked CSR slots point at an all-zero row hs[n];
// accumulation is unconditional adds (exact +0.0) -> no mask regs, all 16
// gathers fit in flight. (3) acquire fence leader-only: 1 wbl2+inv per
// block per barrier instead of per wave (4x fewer L2 maintenance ops).

#define SLOTS 48
#define NBLK 1024
#define GRPS 32
#define GSIZE (NBLK / GRPS)      // 32
#define ASTRIDE 129
#define WSTRIDE 140

static __device__ __forceinline__ float4 f4add(float4 a, float4 b) {
    return make_float4(a.x + b.x, a.y + b.y, a.z + b.z, a.w + b.w);
}
static __device__ __forceinline__ float4 f4fma(float s, float4 a, float4 acc) {
    return make_float4(fmaf(s, a.x, acc.x), fmaf(s, a.y, acc.y),
                       fmaf(s, a.z, acc.z), fmaf(s, a.w, acc.w));
}

// ---- grid barrier: hierarchical arrive + write-once release flag --------
// Arrive: release fetch_add on per-group line (wbl2 flushes this XCD's
// dirty lines, incl. all co-resident blocks' stores, before the signal).
// Last arriver of a group bumps g2; last group publishes `phase` to rel.
// Spin: RELAXED agent loads + s_sleep (no cache maintenance per poll).
// Acquire: leader-only __threadfence (inv covers this CU's L1 + XCD's L2)
// BEFORE the closing __syncthreads releases the block's other waves.
static __device__ __forceinline__ void gridbar(int* barmem, int phase) {
    __syncthreads();
    if (threadIdx.x == 0) {
        int* arrive = barmem + (blockIdx.x & (GRPS - 1)) * 32;
        int* g2     = barmem + GRPS * 32;
        int* rel    = barmem + GRPS * 32 + 32;
        int old = __hip_atomic_fetch_add(arrive, 1, __ATOMIC_RELEASE,
                                         __HIP_MEMORY_SCOPE_AGENT);
        if (old == phase * GSIZE - 1) {
            int o2 = __hip_atomic_fetch_add(g2, 1, __ATOMIC_RELAXED,
                                            __HIP_MEMORY_SCOPE_AGENT);
            if (o2 == phase * GRPS - 1)
                __hip_atomic_store(rel, phase, __ATOMIC_RELEASE,
                                   __HIP_MEMORY_SCOPE_AGENT);
        }
        while (__hip_atomic_load(rel, __ATOMIC_RELAXED,
                                 __HIP_MEMORY_SCOPE_AGENT) < phase)
            __builtin_amdgcn_s_sleep(16);
        __threadfence();  // acquire: one inv per block, pre-release of waves
    }
    __syncthreads();
}

// ---- weight fold: row r of [embW; embb] @ W0 -> W01/b01 (verbatim) ----
static __device__ __forceinline__ void fold_row(
    const float* __restrict__ embW, const float* __restrict__ embb,
    const float* __restrict__ W0, float* __restrict__ W01,
    float* __restrict__ b01, float* smem)
{
    float* rs   = smem;        // 128 floats
    float* part = smem + 128;  // 256 floats
    const int r = blockIdx.x;  // 0..128; r==128 -> bias row
    const int t = threadIdx.x;
    const int c = t & 127, q = t >> 7;
    if (t < 128) rs[t] = (r < 128) ? embW[r * 128 + t] : embb[t];
    __syncthreads();
    float s = 0.f;
    const int k0 = q * 64;
#pragma unroll 8
    for (int k = k0; k < k0 + 64; k++) s = fmaf(rs[k], W0[k * 128 + c], s);
    part[t] = s;
    __syncthreads();
    if (q == 0) {
        float v = part[c] + part[c + 128];
        if (r < 128) W01[r * 128 + c] = v;
        else         b01[c] = v;
    }
    __syncthreads();
}

// ---- GEMM tile: rows [bid*128, bid*128+128) of [n,128]@[128,128] --------
// Proven structure: 8x8 microtile, single-buffered LDS, register prefetch.
// ASTRIDE=129 (==1 mod 32, same bank rotation as proven 257, half LDS).
static __device__ __forceinline__ void gemm_tile(
    const float* __restrict__ A, const float* __restrict__ W,
    const float* __restrict__ bias, const int* __restrict__ rowdeg,
    float* __restrict__ out, float* __restrict__ As, float* __restrict__ Ws)
{
    const int tid  = threadIdx.x;
    const int rb   = blockIdx.x * 128;
    const int tc   = tid & 15;
    const int tr   = tid >> 4;
    const int colg = tc * 8;
    const int cswz = colg + ((colg >> 5) << 2);
    const int rowg = tr * 8;

    const int a_kq = tid & 7;
    const int a_m  = tid >> 3;
    const int w_c  = (tid & 31) * 4;
    const int w_cs = w_c + ((w_c >> 5) << 2);
    const int w_k  = tid >> 5;

    float acc[8][8];
#pragma unroll
    for (int i = 0; i < 8; i++)
#pragma unroll
        for (int j = 0; j < 8; j++) acc[i][j] = 0.f;

    float4 areg[4], wreg[4];
#pragma unroll
    for (int t = 0; t < 4; t++)
        areg[t] = *(const float4*)&A[(size_t)(rb + t * 32 + a_m) * 128 + a_kq * 4];
#pragma unroll
    for (int t = 0; t < 4; t++)
        wreg[t] = *(const float4*)&W[(size_t)(t * 8 + w_k) * 128 + w_c];

#pragma unroll 1
    for (int k0 = 0; k0 < 128; k0 += 32) {
#pragma unroll
        for (int t = 0; t < 4; t++) {
            const int m = t * 32 + a_m;
            const float4 av = areg[t];
            As[(a_kq * 4 + 0) * ASTRIDE + m] = av.x;
            As[(a_kq * 4 + 1) * ASTRIDE + m] = av.y;
            As[(a_kq * 4 + 2) * ASTRIDE + m] = av.z;
            As[(a_kq * 4 + 3) * ASTRIDE + m] = av.w;
        }
#pragma unroll
        for (int t = 0; t < 4; t++)
            *(float4*)&Ws[(t * 8 + w_k) * WSTRIDE + w_cs] = wreg[t];
        __syncthreads();
        if (k0 < 96) {
#pragma unroll
            for (int t = 0; t < 4; t++)
                areg[t] = *(const float4*)&A[(size_t)(rb + t * 32 + a_m) * 128 + k0 + 32 + a_kq * 4];
#pragma unroll
            for (int t = 0; t < 4; t++)
                wreg[t] = *(const float4*)&W[(size_t)(k0 + 32 + t * 8 + w_k) * 128 + w_c];
        }
#pragma unroll 8
        for (int kk = 0; kk < 32; kk++) {
            float4 a0 = *(const float4*)&As[kk * ASTRIDE + rowg];
            float4 a1 = *(const float4*)&As[kk * ASTRIDE + rowg + 4];
            float4 b0 = *(const float4*)&Ws[kk * WSTRIDE + cswz];
            float4 b1 = *(const float4*)&Ws[kk * WSTRIDE + cswz + 4];
            float av[8] = {a0.x, a0.y, a0.z, a0.w, a1.x, a1.y, a1.z, a1.w};
            float bv[8] = {b0.x, b0.y, b0.z, b0.w, b1.x, b1.y, b1.z, b1.w};
#pragma unroll
            for (int i = 0; i < 8; i++)
#pragma unroll
                for (int j = 0; j < 8; j++) acc[i][j] = fmaf(av[i], bv[j], acc[i][j]);
        }
        __syncthreads();
    }

    float4 bb0 = make_float4(0.f, 0.f, 0.f, 0.f), bb1 = bb0;
    if (bias) {
        bb0 = *(const float4*)&bias[colg];
        bb1 = *(const float4*)&bias[colg + 4];
    }
#pragma unroll
    for (int i = 0; i < 8; i++) {
        const int row  = rb + rowg + i;
        const float sc = rowdeg ? rsqrtf((float)(rowdeg[row] + 1)) : 1.f;
        float4 o0, o1;
        o0.x = (acc[i][0] + bb0.x) * sc;  o0.y = (acc[i][1] + bb0.y) * sc;
        o0.z = (acc[i][2] + bb0.z) * sc;  o0.w = (acc[i][3] + bb0.w) * sc;
        o1.x = (acc[i][4] + bb1.x) * sc;  o1.y = (acc[i][5] + bb1.y) * sc;
        o1.z = (acc[i][6] + bb1.z) * sc;  o1.w = (acc[i][7] + bb1.w) * sc;
        *(float4*)&out[(size_t)row * 128 + colg]     = o0;
        *(float4*)&out[(size_t)row * 128 + colg + 4] = o1;
    }
}

// ---- aggregation: grid-stride, zero-row masked gather (no mask regs) ----
// h_out[i] = relu((hs[i] + sum_{src} hs[src]) * rsqrt(deg+1) + b)
// Padded CSR slots beyond deg are redirected to hs[n] (all-zero row) ->
// unconditional sum of 16 gathers is exact; 16 float4 loads stay in
// flight (fits the 128-VGPR budget from launch_bounds(256,4)).
static __device__ __forceinline__ void agg_phase(
    const float* __restrict__ hs, const int* __restrict__ csr_pad,
    const int* __restrict__ cnt, const float* __restrict__ bias,
    float* __restrict__ hout, const float* __restrict__ pool_p,
    float* __restrict__ scores, int n)
{
    const int grp  = threadIdx.x >> 5;
    const int lane = threadIdx.x & 31;
    const float4* __restrict__ hv = (const float4*)hs;
    const float4 bb = ((const float4*)bias)[lane];
    const int ngrp = n >> 3;

    for (int v = blockIdx.x; v < ngrp; v += NBLK) {
        const int node = v * 8 + grp;
        const int deg  = cnt[node];
        const int e0   = node * SLOTS;

        int ix[16];
#pragma unroll
        for (int j = 0; j < 16; j++) {
            const int raw = csr_pad[e0 + j];     // always in-bounds memory
            ix[j] = (j < deg) ? raw : n;         // poison -> zero row
        }

        float4 self = hv[(size_t)node * 32 + lane];
        float4 r[16];
#pragma unroll
        for (int j = 0; j < 16; j++)
            r[j] = hv[(size_t)ix[j] * 32 + lane];
        asm volatile("" ::: "memory");  // keep the 16 loads in flight

        float4 a0 = self;
        float4 a1 = make_float4(0.f, 0.f, 0.f, 0.f);
        float4 a2 = a1, a3 = a1;
#pragma unroll
        for (int j = 0; j < 16; j += 4) {
            a0 = f4add(a0, r[j + 0]);
            a1 = f4add(a1, r[j + 1]);
            a2 = f4add(a2, r[j + 2]);
            a3 = f4add(a3, r[j + 3]);
        }
        const int dcap = deg < SLOTS ? deg : SLOTS;
        for (int j = 16; j < dcap; j++) {  // rare tail (deg > 16)
            a1 = f4add(a1, hv[(size_t)csr_pad[e0 + j] * 32 + lane]);
        }

        float4 s = f4add(f4add(a0, a1), f4add(a2, a3));
        const float dv = rsqrtf((float)(deg + 1));
        float4 o;
        o.x = fmaxf(fmaf(s.x, dv, bb.x), 0.f);
        o.y = fmaxf(fmaf(s.y, dv, bb.y), 0.f);
        o.z = fmaxf(fmaf(s.z, dv, bb.z), 0.f);
        o.w = fmaxf(fmaf(s.w, dv, bb.w), 0.f);
        ((float4*)hout)[(size_t)node * 32 + lane] = o;

        if (scores) {  // wave-uniform branch (fused pooling score)
            float4 pv = ((const float4*)pool_p)[lane];
            float d  = o.x * pv.x + o.y * pv.y + o.z * pv.z + o.w * pv.w;
            float nn = pv.x * pv.x + pv.y * pv.y + pv.z * pv.z + pv.w * pv.w;
#pragma unroll
            for (int off = 16; off > 0; off >>= 1) {
                d  += __shfl_xor(d, off);
                nn += __shfl_xor(nn, off);
            }
            if (lane == 0) scores[node] = d * rsqrtf(nn);
        }
    }
}

// =========================== persistent mega-kernel =========================
// 1024 blocks = 4/CU exact capacity (LDS 34.4KB, VGPR<=128 by launch bound).
// P0: edge scatter (all) + weight fold (0..128) + zero-row init | bar 1
// P1: gemm0 (0..511)                                            | bar 2
// P2..: aggregate l / gemm l+1 alternating                      | bar 3..6
__global__ void __launch_bounds__(256, 4)
mega(
    const int* __restrict__ src, const int* __restrict__ dst,
    int* __restrict__ cnt, int* __restrict__ csr_pad, int* __restrict__ bar,
    const float* __restrict__ x,
    const float* __restrict__ embW, const float* __restrict__ embb,
    const float* __restrict__ gcnW, const float* __restrict__ gcnb,
    float* __restrict__ W01, float* __restrict__ b01,
    float* __restrict__ hs, float* __restrict__ h,
    const float* __restrict__ poolp, float* __restrict__ scores,
    int E, int n)
{
    __shared__ float smem[32 * ASTRIDE + 32 * WSTRIDE];  // 34432 B
    float* As = smem;
    float* Ws = smem + 32 * ASTRIDE;

    // ---- P0: CSR scatter (2 exact iters) + fold + zero-row init ----
    for (int e = blockIdx.x * 256 + threadIdx.x; e < E; e += NBLK * 256) {
        int d = dst[e];
        int r = atomicAdd(&cnt[d], 1);
        if (r < SLOTS) csr_pad[d * SLOTS + r] = src[e];
    }
    if (blockIdx.x == 200 && threadIdx.x < 128)
        hs[(size_t)n * 128 + threadIdx.x] = 0.f;   // the gather zero row
    if (blockIdx.x < 129) fold_row(embW, embb, gcnW, W01, b01, smem);
    gridbar(bar, 1);

    // ---- P1: layer-0 GEMM (folded embedding) ----
    if (blockIdx.x < 512) gemm_tile(x, W01, b01, cnt, hs, As, Ws);
    gridbar(bar, 2);

    // ---- P2..: aggregate l, then gemm l+1 ----
    for (int l = 0; l < 3; l++) {
        agg_phase(hs, csr_pad, cnt, gcnb + (size_t)l * 128, h,
                  poolp, (l == 2) ? scores : nullptr, n);
        if (l < 2) {
            gridbar(bar, 3 + 2 * l);
            if (blockIdx.x < 512)
                gemm_tile(h, gcnW + (size_t)(l + 1) * 128 * 128,
                          nullptr, cnt, hs, As, Ws);
            gridbar(bar, 4 + 2 * l);
        }
    }
}

// ==================== TopK pool (k=256 of 512) + MLP head ===================
__global__ __launch_bounds__(512) void topk_mlp(
    const float* __restrict__ scores, const float* __restrict__ h,
    const float* __restrict__ fc1W, const float* __restrict__ fc1b,
    const float* __restrict__ fc2W, const float* __restrict__ fc2b,
    const float* __restrict__ fc3W, const float* __restrict__ fc3b,
    float* __restrict__ out)
{
    __shared__ float s[512];
    __shared__ int   sel[256];
    __shared__ float w[256];
    __shared__ float4 red[512];
    __shared__ float pld[128];
    __shared__ float z1[128];
    __shared__ float z2[64];
    const int g = blockIdx.x;
    const int i = threadIdx.x;
    s[i] = scores[g * 512 + i];
    __syncthreads();
    float si = s[i];
    int rank = 0;
    for (int j = 0; j < 512; j++) {
        float sj = s[j];
        rank += (sj > si) || (sj == si && j < i);
    }
    if (rank < 256) {
        sel[rank] = i;
        w[rank]   = tanhf(si) * (1.f / 256.f);
    }
    __syncthreads();
    const int c   = (i & 31) * 4;
    const int grp = i >> 5;
    float4 acc = make_float4(0.f, 0.f, 0.f, 0.f);
    for (int t = grp; t < 256; t += 16) {
        float wt  = w[t];
        int   idx = sel[t];
        float4 r = *(const float4*)&h[((size_t)g * 512 + idx) * 128 + c];
        acc = f4fma(wt, r, acc);
    }
    red[i] = acc;
    __syncthreads();
    if (i < 256) red[i] = f4add(red[i], red[i + 256]);
    __syncthreads();
    if (i < 128) red[i] = f4add(red[i], red[i + 128]);
    __syncthreads();
    if (i < 64) red[i] = f4add(red[i], red[i + 64]);
    __syncthreads();
    if (i < 32) {
        float4 v = f4add(red[i], red[i + 32]);
        *(float4*)&pld[i * 4] = v;
    }
    __syncthreads();
    if (i < 128) {
        float a = fc1b[i];
        for (int k = 0; k < 128; k++) a += pld[k] * fc1W[k * 128 + i];
        z1[i] = fmaxf(a, 0.f);
    }
    __syncthreads();
    if (i < 64) {
        float b = fc2b[i];
        for (int k = 0; k < 128; k++) b += z1[k] * fc2W[k * 64 + i];
        z2[i] = fmaxf(b, 0.f);
    }
    __syncthreads();
    if (i < 10) {
        float o = fc3b[i];
        for (int k = 0; k < 64; k++) o += z2[k] * fc3W[k * 10 + i];
        out[g * 10 + i] = o;
    }
}

// ============================ Launcher ======================================
extern "C" void kernel_launch(void* const* d_in, const int* in_sizes, int n_in,
                              void* d_out, int out_size, void* d_ws, size_t ws_size,
                              hipStream_t stream)
{
    const float* x     = (const float*)d_in[0];
    const int*   eidx  = (const int*)d_in[1];
    const float* embW  = (const float*)d_in[3];
    const float* embb  = (const float*)d_in[4];
    const float* gcnW  = (const float*)d_in[5];
    const float* gcnb  = (const float*)d_in[6];
    const float* poolp = (const float*)d_in[7];
    const float* fc1W  = (const float*)d_in[8];
    const float* fc1b  = (const float*)d_in[9];
    const float* fc2W  = (const float*)d_in[10];
    const float* fc2b  = (const float*)d_in[11];
    const float* fc3W  = (const float*)d_in[12];
    const float* fc3b  = (const float*)d_in[13];
    float* out = (float*)d_out;

    const int n = in_sizes[0] / 128;   // 65536
    const int E = in_sizes[1] / 2;     // 524288
    const int G = n / 512;             // 128

    const int* src = eidx;
    const int* dst = eidx + E;

    char* ws = (char*)d_ws;
    size_t off = 0;
    auto carve = [&](size_t bytes) {
        void* p = ws + off;
        off += (bytes + 255) & ~(size_t)255;
        return p;
    };
    float* h       = (float*)carve((size_t)n * 128 * 4);
    float* hs      = (float*)carve((size_t)(n + 1) * 128 * 4);  // +zero row
    int*   cnt     = (int*)carve((size_t)n * 4);                // 256-aligned
    int*   bar     = (int*)carve(4608);                         // follows cnt
    int*   csr_pad = (int*)carve((size_t)n * SLOTS * 4);
    float* scores  = (float*)carve((size_t)n * 4);
    float* W01     = (float*)carve(128 * 128 * 4);
    float* b01     = (float*)carve(128 * 4);
    (void)ws_size;

    // zero degree counters + barrier memory in one memset (contiguous)
    hipMemsetAsync(cnt, 0, (size_t)n * 4 + 4608, stream);

    mega<<<NBLK, 256, 0, stream>>>(src, dst, cnt, csr_pad, bar, x,
                                   embW, embb, gcnW, gcnb, W01, b01,
                                   hs, h, poolp, scores, E, n);

    topk_mlp<<<G, 512, 0, stream>>>(scores, h, fc1W, fc1b, fc2W, fc2b,
                                    fc3W, fc3b, out);
}

// Round 4
// 401.937 us; speedup vs baseline: 3.9115x; 2.0892x over previous
//
#include <hip/hip_runtime.h>
#include <hip/hip_bf16.h>
#include <math.h>

// N = 65536 nodes, E = 524288 edges, HID = 128, 128 graphs x 512 nodes
// fp32 throughout: absmax threshold ~9.8e-8 forbids bf16 MFMA.
// ROUND 4: back to the PROVEN multi-dispatch structure (392.8us). Rounds
// 1-3 showed the persistent mega-kernel loses more to barrier skew +
// one-size-fits-all regalloc (r3: launch_bounds(256,4) -> 64 VGPR -> 200MB
// scratch spill traffic) than the ~80us of dispatch boundaries it saves,
// and the relaxed-agent spin has a 31ms stall mode. Multi-dispatch gives
// per-kernel register budgets for free.
// Safe carries from r1-r3:
//  - GEMM ASTRIDE 257->129 (==1 mod 32: identical bank rotation, LDS
//    51.2->34.4KB; gains a 4th block/CU iff natural VGPR<=128, else
//    unchanged -- never worse).
//  - Aggregate zero-row gather: poison CSR slots -> all-zero row hs[n],
//    unconditional adds (exact +0.0), NO mask registers, natural VGPR so
//    all 16 gathers stay in flight. Zero row initialized in build kernel.
//  - CSR row loaded as 4x int4 (192B-aligned rows) instead of 16 scalars.

#define SLOTS 48

static __device__ __forceinline__ float4 f4add(float4 a, float4 b) {
    return make_float4(a.x + b.x, a.y + b.y, a.z + b.z, a.w + b.w);
}
static __device__ __forceinline__ float4 f4fma(float s, float4 a, float4 acc) {
    return make_float4(fmaf(s, a.x, acc.x), fmaf(s, a.y, acc.y),
                       fmaf(s, a.z, acc.z), fmaf(s, a.w, acc.w));
}

// ============ Fused: edge count+scatter (blocks 0..EB-1)  +  weight fold ====
// Edge blocks: rank = atomicAdd(cnt[dst]); csr_pad[dst*48+rank] = src.
// Fold blocks (b >= EB): row r of [embW; embb] @ W0 -> W01/b01 (2-way k-split).
// Block EB also zero-inits the gather zero-row hs[n].
__global__ __launch_bounds__(256) void build_graph_fold(
    const int* __restrict__ src, const int* __restrict__ dst,
    int* __restrict__ cnt, int* __restrict__ csr_pad, int E, int EB,
    const float* __restrict__ embW, const float* __restrict__ embb,
    const float* __restrict__ W0, float* __restrict__ W01,
    float* __restrict__ b01, float* __restrict__ zrow)
{
    const int b = blockIdx.x;
    if (b < EB) {
        int e = b * 256 + threadIdx.x;
        if (e < E) {
            int d = dst[e];
            int r = atomicAdd(&cnt[d], 1);
            if (r < SLOTS) csr_pad[d * SLOTS + r] = src[e];
        }
        return;
    }
    // ---- weight fold ----
    __shared__ float rs[128];
    __shared__ float part[256];
    const int r = b - EB;           // 0..128; r==128 -> bias row
    const int t = threadIdx.x;
    if (r == 0 && t < 128) zrow[t] = 0.f;   // gather zero-row init
    const int c = t & 127, q = t >> 7;  // q in {0,1}
    if (t < 128) rs[t] = (r < 128) ? embW[r * 128 + t] : embb[t];
    __syncthreads();
    float s = 0.f;
    const int k0 = q * 64;
#pragma unroll 8
    for (int k = k0; k < k0 + 64; k++) s = fmaf(rs[k], W0[k * 128 + c], s);
    part[t] = s;
    __syncthreads();
    if (q == 0) {
        float v = part[c] + part[c + 128];
        if (r < 128) W01[r * 128 + c] = v;
        else         b01[c] = v;
    }
}

// ============================ GEMM: [n,128] @ [128,128] =====================
// Proven structure (44.4us): BM=128, 256 thr, 8x8 microtile, single-buffered
// LDS, register prefetch. ASTRIDE=129 (==1 mod 32, same bank behavior as the
// proven 257: A-stores uniform 2-way aliasing (free, m136); A-reads 16-lane
// broadcasts) -> LDS 34.4KB, 4th block/CU possible if VGPR<=128.
// WSTRIDE=140 + col swizzle c->c+4*(c>>5) (injective, max 139).
// Epilogue: out = (acc + bias) * rsqrt(deg[row]+1)  (bias/rowdeg nullable)
#define ASTRIDE 129
#define WSTRIDE 140
__global__ __launch_bounds__(256) void gemm128(
    const float* __restrict__ A, const float* __restrict__ W,
    const float* __restrict__ bias, const int* __restrict__ rowdeg,
    float* __restrict__ out, int n)
{
    __shared__ float As[32 * ASTRIDE];  // [k][m] transposed
    __shared__ float Ws[32 * WSTRIDE];  // [k][c'] swizzled
    const int tid  = threadIdx.x;
    const int rb   = blockIdx.x * 128;
    const int tc   = tid & 15;
    const int tr   = tid >> 4;
    const int colg = tc * 8;
    const int cswz = colg + ((colg >> 5) << 2);
    const int rowg = tr * 8;

    const int a_kq = tid & 7;
    const int a_m  = tid >> 3;
    const int w_c  = (tid & 31) * 4;
    const int w_cs = w_c + ((w_c >> 5) << 2);
    const int w_k  = tid >> 5;

    float acc[8][8];
#pragma unroll
    for (int i = 0; i < 8; i++)
#pragma unroll
        for (int j = 0; j < 8; j++) acc[i][j] = 0.f;

    float4 areg[4], wreg[4];
#pragma unroll
    for (int t = 0; t < 4; t++)
        areg[t] = *(const float4*)&A[(size_t)(rb + t * 32 + a_m) * 128 + a_kq * 4];
#pragma unroll
    for (int t = 0; t < 4; t++)
        wreg[t] = *(const float4*)&W[(size_t)(t * 8 + w_k) * 128 + w_c];

#pragma unroll 1
    for (int k0 = 0; k0 < 128; k0 += 32) {
#pragma unroll
        for (int t = 0; t < 4; t++) {
            const int m = t * 32 + a_m;
            const float4 av = areg[t];
            As[(a_kq * 4 + 0) * ASTRIDE + m] = av.x;
            As[(a_kq * 4 + 1) * ASTRIDE + m] = av.y;
            As[(a_kq * 4 + 2) * ASTRIDE + m] = av.z;
            As[(a_kq * 4 + 3) * ASTRIDE + m] = av.w;
        }
#pragma unroll
        for (int t = 0; t < 4; t++)
            *(float4*)&Ws[(t * 8 + w_k) * WSTRIDE + w_cs] = wreg[t];
        __syncthreads();
        if (k0 < 96) {
#pragma unroll
            for (int t = 0; t < 4; t++)
                areg[t] = *(const float4*)&A[(size_t)(rb + t * 32 + a_m) * 128 + k0 + 32 + a_kq * 4];
#pragma unroll
            for (int t = 0; t < 4; t++)
                wreg[t] = *(const float4*)&W[(size_t)(k0 + 32 + t * 8 + w_k) * 128 + w_c];
        }
#pragma unroll 8
        for (int kk = 0; kk < 32; kk++) {
            float4 a0 = *(const float4*)&As[kk * ASTRIDE + rowg];
            float4 a1 = *(const float4*)&As[kk * ASTRIDE + rowg + 4];
            float4 b0 = *(const float4*)&Ws[kk * WSTRIDE + cswz];
            float4 b1 = *(const float4*)&Ws[kk * WSTRIDE + cswz + 4];
            float av[8] = {a0.x, a0.y, a0.z, a0.w, a1.x, a1.y, a1.z, a1.w};
            float bv[8] = {b0.x, b0.y, b0.z, b0.w, b1.x, b1.y, b1.z, b1.w};
#pragma unroll
            for (int i = 0; i < 8; i++)
#pragma unroll
                for (int j = 0; j < 8; j++) acc[i][j] = fmaf(av[i], bv[j], acc[i][j]);
        }
        __syncthreads();
    }

    float4 bb0 = make_float4(0.f, 0.f, 0.f, 0.f), bb1 = bb0;
    if (bias) {
        bb0 = *(const float4*)&bias[colg];
        bb1 = *(const float4*)&bias[colg + 4];
    }
#pragma unroll
    for (int i = 0; i < 8; i++) {
        const int row  = rb + rowg + i;
        const float sc = rowdeg ? rsqrtf((float)(rowdeg[row] + 1)) : 1.f;
        float4 o0, o1;
        o0.x = (acc[i][0] + bb0.x) * sc;  o0.y = (acc[i][1] + bb0.y) * sc;
        o0.z = (acc[i][2] + bb0.z) * sc;  o0.w = (acc[i][3] + bb0.w) * sc;
        o1.x = (acc[i][4] + bb1.x) * sc;  o1.y = (acc[i][5] + bb1.y) * sc;
        o1.z = (acc[i][6] + bb1.z) * sc;  o1.w = (acc[i][7] + bb1.w) * sc;
        *(float4*)&out[(size_t)row * 128 + colg]     = o0;
        *(float4*)&out[(size_t)row * 128 + colg + 4] = o1;
    }
}

// ============================ Aggregation ===================================
// h_out[i] = relu((hs[i] + sum_{src in in(i)} hs[src]) * rsqrt(deg+1) + b)
// Padded CSR: slots beyond deg are redirected to the all-zero row hs[n] ->
// unconditional sum of 16 gathers is exact (+0.0), no mask registers, all
// 16 float4 loads stay in flight. CSR row read as 4x int4 (rows 192B-aligned).
// 32 lanes/node (float4 per lane), 8 nodes per 256-thread block; tail loop
// covers deg in (16, SLOTS].
__global__ __launch_bounds__(256) void aggregate(
    const float* __restrict__ hs, const int* __restrict__ csr_pad,
    const int* __restrict__ cnt, const float* __restrict__ bias,
    float* __restrict__ hout,
    const float* __restrict__ pool_p, float* __restrict__ scores, int n)
{
    const int grp  = threadIdx.x >> 5;
    const int lane = threadIdx.x & 31;
    const int node = blockIdx.x * 8 + grp;
    const float4* __restrict__ hv = (const float4*)hs;

    const int deg = cnt[node];
    const int e0  = node * SLOTS;

    int4 c4[4];
#pragma unroll
    for (int q = 0; q < 4; q++)
        c4[q] = *(const int4*)&csr_pad[e0 + q * 4];
    int ix[16] = {c4[0].x, c4[0].y, c4[0].z, c4[0].w,
                  c4[1].x, c4[1].y, c4[1].z, c4[1].w,
                  c4[2].x, c4[2].y, c4[2].z, c4[2].w,
                  c4[3].x, c4[3].y, c4[3].z, c4[3].w};
#pragma unroll
    for (int j = 0; j < 16; j++)
        ix[j] = (j < deg) ? ix[j] : n;       // poison -> zero row

    float4 self = hv[(size_t)node * 32 + lane];
    float4 r[16];
#pragma unroll
    for (int j = 0; j < 16; j++)
        r[j] = hv[(size_t)ix[j] * 32 + lane];
    asm volatile("" ::: "memory");  // keep the 16 loads in flight before use

    float4 a0 = self;
    float4 a1 = make_float4(0.f, 0.f, 0.f, 0.f);
    float4 a2 = a1, a3 = a1;
#pragma unroll
    for (int j = 0; j < 16; j += 4) {
        a0 = f4add(a0, r[j + 0]);
        a1 = f4add(a1, r[j + 1]);
        a2 = f4add(a2, r[j + 2]);
        a3 = f4add(a3, r[j + 3]);
    }
    const int dcap = deg < SLOTS ? deg : SLOTS;
    for (int j = 16; j < dcap; j++) {  // rare tail (deg > 16)
        a1 = f4add(a1, hv[(size_t)csr_pad[e0 + j] * 32 + lane]);
    }

    float4 s = f4add(f4add(a0, a1), f4add(a2, a3));
    const float dv = rsqrtf((float)(deg + 1));
    const float4 bb = ((const float4*)bias)[lane];
    float4 o;
    o.x = fmaxf(fmaf(s.x, dv, bb.x), 0.f);
    o.y = fmaxf(fmaf(s.y, dv, bb.y), 0.f);
    o.z = fmaxf(fmaf(s.z, dv, bb.z), 0.f);
    o.w = fmaxf(fmaf(s.w, dv, bb.w), 0.f);
    ((float4*)hout)[(size_t)node * 32 + lane] = o;

    if (scores) {  // wave-uniform branch (fused pooling score)
        float4 pv = ((const float4*)pool_p)[lane];
        float d  = o.x * pv.x + o.y * pv.y + o.z * pv.z + o.w * pv.w;
        float nn = pv.x * pv.x + pv.y * pv.y + pv.z * pv.z + pv.w * pv.w;
#pragma unroll
        for (int off = 16; off > 0; off >>= 1) {
            d  += __shfl_xor(d, off);
            nn += __shfl_xor(nn, off);
        }
        if (lane == 0) scores[node] = d * rsqrtf(nn);
    }
}

// ==================== TopK pool (k=256 of 512) + MLP head ===================
__global__ __launch_bounds__(512) void topk_mlp(
    const float* __restrict__ scores, const float* __restrict__ h,
    const float* __restrict__ fc1W, const float* __restrict__ fc1b,
    const float* __restrict__ fc2W, const float* __restrict__ fc2b,
    const float* __restrict__ fc3W, const float* __restrict__ fc3b,
    float* __restrict__ out)
{
    __shared__ float s[512];
    __shared__ int   sel[256];
    __shared__ float w[256];
    __shared__ float4 red[512];
    __shared__ float pld[128];
    __shared__ float z1[128];
    __shared__ float z2[64];
    const int g = blockIdx.x;
    const int i = threadIdx.x;
    s[i] = scores[g * 512 + i];
    __syncthreads();
    float si = s[i];
    int rank = 0;
    for (int j = 0; j < 512; j++) {
        float sj = s[j];
        rank += (sj > si) || (sj == si && j < i);
    }
    if (rank < 256) {
        sel[rank] = i;
        w[rank]   = tanhf(si) * (1.f / 256.f);
    }
    __syncthreads();
    const int c   = (i & 31) * 4;
    const int grp = i >> 5;
    float4 acc = make_float4(0.f, 0.f, 0.f, 0.f);
    for (int t = grp; t < 256; t += 16) {
        float wt  = w[t];
        int   idx = sel[t];
        float4 r = *(const float4*)&h[((size_t)g * 512 + idx) * 128 + c];
        acc = f4fma(wt, r, acc);
    }
    red[i] = acc;
    __syncthreads();
    if (i < 256) red[i] = f4add(red[i], red[i + 256]);
    __syncthreads();
    if (i < 128) red[i] = f4add(red[i], red[i + 128]);
    __syncthreads();
    if (i < 64) red[i] = f4add(red[i], red[i + 64]);
    __syncthreads();
    if (i < 32) {
        float4 v = f4add(red[i], red[i + 32]);
        *(float4*)&pld[i * 4] = v;
    }
    __syncthreads();
    if (i < 128) {
        float a = fc1b[i];
        for (int k = 0; k < 128; k++) a += pld[k] * fc1W[k * 128 + i];
        z1[i] = fmaxf(a, 0.f);
    }
    __syncthreads();
    if (i < 64) {
        float b = fc2b[i];
        for (int k = 0; k < 128; k++) b += z1[k] * fc2W[k * 64 + i];
        z2[i] = fmaxf(b, 0.f);
    }
    __syncthreads();
    if (i < 10) {
        float o = fc3b[i];
        for (int k = 0; k < 64; k++) o += z2[k] * fc3W[k * 10 + i];
        out[g * 10 + i] = o;
    }
}

// ============================ Launcher ======================================
extern "C" void kernel_launch(void* const* d_in, const int* in_sizes, int n_in,
                              void* d_out, int out_size, void* d_ws, size_t ws_size,
                              hipStream_t stream)
{
    const float* x     = (const float*)d_in[0];
    const int*   eidx  = (const int*)d_in[1];
    const float* embW  = (const float*)d_in[3];
    const float* embb  = (const float*)d_in[4];
    const float* gcnW  = (const float*)d_in[5];
    const float* gcnb  = (const float*)d_in[6];
    const float* poolp = (const float*)d_in[7];
    const float* fc1W  = (const float*)d_in[8];
    const float* fc1b  = (const float*)d_in[9];
    const float* fc2W  = (const float*)d_in[10];
    const float* fc2b  = (const float*)d_in[11];
    const float* fc3W  = (const float*)d_in[12];
    const float* fc3b  = (const float*)d_in[13];
    float* out = (float*)d_out;

    const int n = in_sizes[0] / 128;   // 65536
    const int E = in_sizes[1] / 2;     // 524288
    const int G = n / 512;             // 128

    const int* src = eidx;
    const int* dst = eidx + E;

    char* ws = (char*)d_ws;
    size_t off = 0;
    auto carve = [&](size_t bytes) {
        void* p = ws + off;
        off += (bytes + 255) & ~(size_t)255;
        return p;
    };
    float* h       = (float*)carve((size_t)n * 128 * 4);
    float* hs      = (float*)carve((size_t)(n + 1) * 128 * 4);  // +zero row
    int*   cnt     = (int*)carve((size_t)n * 4);
    int*   csr_pad = (int*)carve((size_t)n * SLOTS * 4);
    float* scores  = (float*)carve((size_t)n * 4);
    float* W01     = (float*)carve(128 * 128 * 4);
    float* b01     = (float*)carve(128 * 4);
    (void)ws_size;

    const int EB = E / 256;            // 2048 edge blocks

    // ---- zero degree counters, then fused CSR build + weight fold ----
    hipMemsetAsync(cnt, 0, (size_t)n * 4, stream);
    build_graph_fold<<<EB + 129, 256, 0, stream>>>(
        src, dst, cnt, csr_pad, E, EB, embW, embb, gcnW, W01, b01,
        hs + (size_t)n * 128);

    // ---- layer 0 (folded embedding) ----
    gemm128<<<n / 128, 256, 0, stream>>>(x, W01, b01, cnt, hs, n);
    aggregate<<<n / 8, 256, 0, stream>>>(hs, csr_pad, cnt, gcnb, h,
                                         poolp, nullptr, n);

    // ---- layers 1,2 (score fused into last aggregate) ----
    for (int l = 1; l < 3; l++) {
        gemm128<<<n / 128, 256, 0, stream>>>(h, gcnW + (size_t)l * 128 * 128,
                                             nullptr, cnt, hs, n);
        aggregate<<<n / 8, 256, 0, stream>>>(
            hs, csr_pad, cnt, gcnb + (size_t)l * 128, h,
            poolp, (l == 2) ? scores : nullptr, n);
    }

    // ---- fused topk pool + MLP ----
    topk_mlp<<<G, 512, 0, stream>>>(scores, h, fc1W, fc1b, fc2W, fc2b,
                                    fc3W, fc3b, out);
}

// Round 5
// 353.465 us; speedup vs baseline: 4.4479x; 1.1371x over previous
//
#include <hip/hip_runtime.h>
#include <hip/hip_bf16.h>
#include <math.h>

// N = 65536 nodes, E = 524288 edges, HID = 128, 128 graphs x 512 nodes
// fp32 throughout: absmax threshold ~9.8e-8 forbids bf16 MFMA.
// ROUND 5: fuse aggregate_l + gemm_{l+1} (layers 0->1, 1->2) into one
// kernel, NO grid sync needed: a GEMM tile's A-rows are tile-local
// aggregations over the globally-complete hs of the previous dispatch.
// Wins: 2 fewer boundaries (~10us each), no h round-trip (33MB wr + 33MB rd
// per fused layer), and VMEM-heavy agg panels overlap VALU-heavy gemm
// panels across the 2 resident blocks/CU. Aggregation is per-feature
// independent -> done per 32-k panel straight into As[k][m]; CSR indices
// cached in LDS (stride 17 -> conflict-free). hs ping-pongs between two
// buffers (no read/write race). gemm0, last aggregate, topk: proven r4
// kernels, byte-identical.

#define SLOTS 48

static __device__ __forceinline__ float4 f4add(float4 a, float4 b) {
    return make_float4(a.x + b.x, a.y + b.y, a.z + b.z, a.w + b.w);
}
static __device__ __forceinline__ float4 f4fma(float s, float4 a, float4 acc) {
    return make_float4(fmaf(s, a.x, acc.x), fmaf(s, a.y, acc.y),
                       fmaf(s, a.z, acc.z), fmaf(s, a.w, acc.w));
}

// ============ Fused: edge count+scatter (blocks 0..EB-1)  +  weight fold ====
__global__ __launch_bounds__(256) void build_graph_fold(
    const int* __restrict__ src, const int* __restrict__ dst,
    int* __restrict__ cnt, int* __restrict__ csr_pad, int E, int EB,
    const float* __restrict__ embW, const float* __restrict__ embb,
    const float* __restrict__ W0, float* __restrict__ W01,
    float* __restrict__ b01, float* __restrict__ zrowA,
    float* __restrict__ zrowB)
{
    const int b = blockIdx.x;
    if (b < EB) {
        int e = b * 256 + threadIdx.x;
        if (e < E) {
            int d = dst[e];
            int r = atomicAdd(&cnt[d], 1);
            if (r < SLOTS) csr_pad[d * SLOTS + r] = src[e];
        }
        return;
    }
    // ---- weight fold ----
    __shared__ float rs[128];
    __shared__ float part[256];
    const int r = b - EB;           // 0..128; r==128 -> bias row
    const int t = threadIdx.x;
    if (r == 0 && t < 128) { zrowA[t] = 0.f; zrowB[t] = 0.f; }
    const int c = t & 127, q = t >> 7;  // q in {0,1}
    if (t < 128) rs[t] = (r < 128) ? embW[r * 128 + t] : embb[t];
    __syncthreads();
    float s = 0.f;
    const int k0 = q * 64;
#pragma unroll 8
    for (int k = k0; k < k0 + 64; k++) s = fmaf(rs[k], W0[k * 128 + c], s);
    part[t] = s;
    __syncthreads();
    if (q == 0) {
        float v = part[c] + part[c + 128];
        if (r < 128) W01[r * 128 + c] = v;
        else         b01[c] = v;
    }
}

// ============================ GEMM: [n,128] @ [128,128] =====================
// Proven structure (44us): BM=128, 256 thr, 8x8 microtile, single-buffered
// LDS, register prefetch. ASTRIDE=129 (==1 mod 32). WSTRIDE=140 + col
// swizzle c->c+4*(c>>5). Epilogue: out = (acc + bias) * rsqrt(deg[row]+1).
#define ASTRIDE 129
#define WSTRIDE 140
__global__ __launch_bounds__(256) void gemm128(
    const float* __restrict__ A, const float* __restrict__ W,
    const float* __restrict__ bias, const int* __restrict__ rowdeg,
    float* __restrict__ out, int n)
{
    __shared__ float As[32 * ASTRIDE];  // [k][m] transposed
    __shared__ float Ws[32 * WSTRIDE];  // [k][c'] swizzled
    const int tid  = threadIdx.x;
    const int rb   = blockIdx.x * 128;
    const int tc   = tid & 15;
    const int tr   = tid >> 4;
    const int colg = tc * 8;
    const int cswz = colg + ((colg >> 5) << 2);
    const int rowg = tr * 8;

    const int a_kq = tid & 7;
    const int a_m  = tid >> 3;
    const int w_c  = (tid & 31) * 4;
    const int w_cs = w_c + ((w_c >> 5) << 2);
    const int w_k  = tid >> 5;

    float acc[8][8];
#pragma unroll
    for (int i = 0; i < 8; i++)
#pragma unroll
        for (int j = 0; j < 8; j++) acc[i][j] = 0.f;

    float4 areg[4], wreg[4];
#pragma unroll
    for (int t = 0; t < 4; t++)
        areg[t] = *(const float4*)&A[(size_t)(rb + t * 32 + a_m) * 128 + a_kq * 4];
#pragma unroll
    for (int t = 0; t < 4; t++)
        wreg[t] = *(const float4*)&W[(size_t)(t * 8 + w_k) * 128 + w_c];

#pragma unroll 1
    for (int k0 = 0; k0 < 128; k0 += 32) {
#pragma unroll
        for (int t = 0; t < 4; t++) {
            const int m = t * 32 + a_m;
            const float4 av = areg[t];
            As[(a_kq * 4 + 0) * ASTRIDE + m] = av.x;
            As[(a_kq * 4 + 1) * ASTRIDE + m] = av.y;
            As[(a_kq * 4 + 2) * ASTRIDE + m] = av.z;
            As[(a_kq * 4 + 3) * ASTRIDE + m] = av.w;
        }
#pragma unroll
        for (int t = 0; t < 4; t++)
            *(float4*)&Ws[(t * 8 + w_k) * WSTRIDE + w_cs] = wreg[t];
        __syncthreads();
        if (k0 < 96) {
#pragma unroll
            for (int t = 0; t < 4; t++)
                areg[t] = *(const float4*)&A[(size_t)(rb + t * 32 + a_m) * 128 + k0 + 32 + a_kq * 4];
#pragma unroll
            for (int t = 0; t < 4; t++)
                wreg[t] = *(const float4*)&W[(size_t)(k0 + 32 + t * 8 + w_k) * 128 + w_c];
        }
#pragma unroll 8
        for (int kk = 0; kk < 32; kk++) {
            float4 a0 = *(const float4*)&As[kk * ASTRIDE + rowg];
            float4 a1 = *(const float4*)&As[kk * ASTRIDE + rowg + 4];
            float4 b0 = *(const float4*)&Ws[kk * WSTRIDE + cswz];
            float4 b1 = *(const float4*)&Ws[kk * WSTRIDE + cswz + 4];
            float av[8] = {a0.x, a0.y, a0.z, a0.w, a1.x, a1.y, a1.z, a1.w};
            float bv[8] = {b0.x, b0.y, b0.z, b0.w, b1.x, b1.y, b1.z, b1.w};
#pragma unroll
            for (int i = 0; i < 8; i++)
#pragma unroll
                for (int j = 0; j < 8; j++) acc[i][j] = fmaf(av[i], bv[j], acc[i][j]);
        }
        __syncthreads();
    }

    float4 bb0 = make_float4(0.f, 0.f, 0.f, 0.f), bb1 = bb0;
    if (bias) {
        bb0 = *(const float4*)&bias[colg];
        bb1 = *(const float4*)&bias[colg + 4];
    }
#pragma unroll
    for (int i = 0; i < 8; i++) {
        const int row  = rb + rowg + i;
        const float sc = rowdeg ? rsqrtf((float)(rowdeg[row] + 1)) : 1.f;
        float4 o0, o1;
        o0.x = (acc[i][0] + bb0.x) * sc;  o0.y = (acc[i][1] + bb0.y) * sc;
        o0.z = (acc[i][2] + bb0.z) * sc;  o0.w = (acc[i][3] + bb0.w) * sc;
        o1.x = (acc[i][4] + bb1.x) * sc;  o1.y = (acc[i][5] + bb1.y) * sc;
        o1.z = (acc[i][6] + bb1.z) * sc;  o1.w = (acc[i][7] + bb1.w) * sc;
        *(float4*)&out[(size_t)row * 128 + colg]     = o0;
        *(float4*)&out[(size_t)row * 128 + colg + 4] = o1;
    }
}

// ================== FUSED aggregate_l + gemm_{l+1} ==========================
// Per block: 128 nodes [rb, rb+128). For each 32-k panel p:
//   agg: A_row[m][k] = relu((hs_in[m][k] + sum_src hs_in[src][k])*dinv[m]+b[k])
//        written transposed into As[k][m] (2-way store aliasing = free)
//   gemm: acc += As-panel @ Ws-panel (proven inner loop)
// Epilogue: hs_out[row] = acc * dinv[row]  (source-side scaling, no bias).
// CSR indices clamped (poison -> zero row n) and cached in LDS stride 17.
__global__ __launch_bounds__(256) void agg_gemm(
    const float* __restrict__ hs_in, const int* __restrict__ csr_pad,
    const int* __restrict__ cnt, const float* __restrict__ aggb,
    const float* __restrict__ W, float* __restrict__ hs_out, int n)
{
    __shared__ int   s_idx[128 * 17];   // clamped CSR, stride 17 (bank-free)
    __shared__ float s_dinv[128];
    __shared__ int   s_deg[128];
    __shared__ float As[32 * ASTRIDE];
    __shared__ float Ws[32 * WSTRIDE];

    const int tid = threadIdx.x;
    const int rb  = blockIdx.x * 128;
    const float4* __restrict__ hv = (const float4*)hs_in;

    if (tid < 128) {
        int d = cnt[rb + tid];
        s_deg[tid]  = d;
        s_dinv[tid] = rsqrtf((float)(d + 1));
    }
    {   // load + clamp CSR: thread t -> node t>>1, slots (t&1)*8 .. +7
        const int m    = tid >> 1;
        const int hf   = (tid & 1) * 8;
        const int node = rb + m;
        const int4 cA = *(const int4*)&csr_pad[node * SLOTS + hf];
        const int4 cB = *(const int4*)&csr_pad[node * SLOTS + hf + 4];
        const int  d  = cnt[node];
        int* row = &s_idx[m * 17 + hf];
        row[0] = (hf + 0 < d) ? cA.x : n;
        row[1] = (hf + 1 < d) ? cA.y : n;
        row[2] = (hf + 2 < d) ? cA.z : n;
        row[3] = (hf + 3 < d) ? cA.w : n;
        row[4] = (hf + 4 < d) ? cB.x : n;
        row[5] = (hf + 5 < d) ? cB.y : n;
        row[6] = (hf + 6 < d) ? cB.z : n;
        row[7] = (hf + 7 < d) ? cB.w : n;
    }
    __syncthreads();

    // gemm thread mapping (identical to gemm128)
    const int tc   = tid & 15;
    const int tr   = tid >> 4;
    const int colg = tc * 8;
    const int cswz = colg + ((colg >> 5) << 2);
    const int rowg = tr * 8;
    const int w_c  = (tid & 31) * 4;
    const int w_cs = w_c + ((w_c >> 5) << 2);
    const int w_k  = tid >> 5;
    // agg thread mapping: 8 lanes/node (float4 each), 32 nodes/pass
    const int ln = tid & 7;
    const int nd = tid >> 3;

    float acc[8][8];
#pragma unroll
    for (int i = 0; i < 8; i++)
#pragma unroll
        for (int j = 0; j < 8; j++) acc[i][j] = 0.f;

#pragma unroll 1
    for (int p = 0; p < 4; p++) {
        // issue W-panel loads early (land under the agg gathers)
        float4 wreg[4];
#pragma unroll
        for (int t = 0; t < 4; t++)
            wreg[t] = *(const float4*)&W[(size_t)(p * 32 + t * 8 + w_k) * 128 + w_c];

        // ---- aggregate this 32-feature panel: 4 passes x 32 nodes ----
        const int fo = p * 8 + ln;          // float4 offset within a row
        const float4 bb = *(const float4*)&aggb[p * 32 + ln * 4];
#pragma unroll 1
        for (int ps = 0; ps < 4; ps++) {
            const int m    = ps * 32 + nd;
            const int node = rb + m;
            const int* rowI = &s_idx[m * 17];
            float4 self = hv[(size_t)node * 32 + fo];
            float4 r[16];
#pragma unroll
            for (int j = 0; j < 16; j++)
                r[j] = hv[(size_t)rowI[j] * 32 + fo];
            asm volatile("" ::: "memory");
            float4 a0 = self;
            float4 a1 = make_float4(0.f, 0.f, 0.f, 0.f);
            float4 a2 = a1, a3 = a1;
#pragma unroll
            for (int j = 0; j < 16; j += 4) {
                a0 = f4add(a0, r[j + 0]);
                a1 = f4add(a1, r[j + 1]);
                a2 = f4add(a2, r[j + 2]);
                a3 = f4add(a3, r[j + 3]);
            }
            const int d    = s_deg[m];
            const int dcap = d < SLOTS ? d : SLOTS;
            for (int j = 16; j < dcap; j++)  // rare tail (deg > 16)
                a1 = f4add(a1, hv[(size_t)csr_pad[node * SLOTS + j] * 32 + fo]);
            float4 s = f4add(f4add(a0, a1), f4add(a2, a3));
            const float dv = s_dinv[m];
            float4 o;
            o.x = fmaxf(fmaf(s.x, dv, bb.x), 0.f);
            o.y = fmaxf(fmaf(s.y, dv, bb.y), 0.f);
            o.z = fmaxf(fmaf(s.z, dv, bb.z), 0.f);
            o.w = fmaxf(fmaf(s.w, dv, bb.w), 0.f);
            const int kb = ln * 4;
            As[(kb + 0) * ASTRIDE + m] = o.x;
            As[(kb + 1) * ASTRIDE + m] = o.y;
            As[(kb + 2) * ASTRIDE + m] = o.z;
            As[(kb + 3) * ASTRIDE + m] = o.w;
        }
#pragma unroll
        for (int t = 0; t < 4; t++)
            *(float4*)&Ws[(t * 8 + w_k) * WSTRIDE + w_cs] = wreg[t];
        __syncthreads();

        // ---- gemm partial-K (proven inner loop) ----
#pragma unroll 8
        for (int kk = 0; kk < 32; kk++) {
            float4 a0 = *(const float4*)&As[kk * ASTRIDE + rowg];
            float4 a1 = *(const float4*)&As[kk * ASTRIDE + rowg + 4];
            float4 b0 = *(const float4*)&Ws[kk * WSTRIDE + cswz];
            float4 b1 = *(const float4*)&Ws[kk * WSTRIDE + cswz + 4];
            float av[8] = {a0.x, a0.y, a0.z, a0.w, a1.x, a1.y, a1.z, a1.w};
            float bv[8] = {b0.x, b0.y, b0.z, b0.w, b1.x, b1.y, b1.z, b1.w};
#pragma unroll
            for (int i = 0; i < 8; i++)
#pragma unroll
                for (int j = 0; j < 8; j++) acc[i][j] = fmaf(av[i], bv[j], acc[i][j]);
        }
        __syncthreads();
    }

    // epilogue: source-side dinv scaling for the next layer, no bias
#pragma unroll
    for (int i = 0; i < 8; i++) {
        const int row  = rb + rowg + i;
        const float sc = s_dinv[rowg + i];
        float4 o0, o1;
        o0.x = acc[i][0] * sc;  o0.y = acc[i][1] * sc;
        o0.z = acc[i][2] * sc;  o0.w = acc[i][3] * sc;
        o1.x = acc[i][4] * sc;  o1.y = acc[i][5] * sc;
        o1.z = acc[i][6] * sc;  o1.w = acc[i][7] * sc;
        *(float4*)&hs_out[(size_t)row * 128 + colg]     = o0;
        *(float4*)&hs_out[(size_t)row * 128 + colg + 4] = o1;
    }
}

// ============================ Aggregation (last layer) ======================
// Proven r4 kernel, byte-identical: zero-row gather, int4 CSR loads,
// fused pooling score.
__global__ __launch_bounds__(256) void aggregate(
    const float* __restrict__ hs, const int* __restrict__ csr_pad,
    const int* __restrict__ cnt, const float* __restrict__ bias,
    float* __restrict__ hout,
    const float* __restrict__ pool_p, float* __restrict__ scores, int n)
{
    const int grp  = threadIdx.x >> 5;
    const int lane = threadIdx.x & 31;
    const int node = blockIdx.x * 8 + grp;
    const float4* __restrict__ hv = (const float4*)hs;

    const int deg = cnt[node];
    const int e0  = node * SLOTS;

    int4 c4[4];
#pragma unroll
    for (int q = 0; q < 4; q++)
        c4[q] = *(const int4*)&csr_pad[e0 + q * 4];
    int ix[16] = {c4[0].x, c4[0].y, c4[0].z, c4[0].w,
                  c4[1].x, c4[1].y, c4[1].z, c4[1].w,
                  c4[2].x, c4[2].y, c4[2].z, c4[2].w,
                  c4[3].x, c4[3].y, c4[3].z, c4[3].w};
#pragma unroll
    for (int j = 0; j < 16; j++)
        ix[j] = (j < deg) ? ix[j] : n;       // poison -> zero row

    float4 self = hv[(size_t)node * 32 + lane];
    float4 r[16];
#pragma unroll
    for (int j = 0; j < 16; j++)
        r[j] = hv[(size_t)ix[j] * 32 + lane];
    asm volatile("" ::: "memory");  // keep the 16 loads in flight before use

    float4 a0 = self;
    float4 a1 = make_float4(0.f, 0.f, 0.f, 0.f);
    float4 a2 = a1, a3 = a1;
#pragma unroll
    for (int j = 0; j < 16; j += 4) {
        a0 = f4add(a0, r[j + 0]);
        a1 = f4add(a1, r[j + 1]);
        a2 = f4add(a2, r[j + 2]);
        a3 = f4add(a3, r[j + 3]);
    }
    const int dcap = deg < SLOTS ? deg : SLOTS;
    for (int j = 16; j < dcap; j++) {  // rare tail (deg > 16)
        a1 = f4add(a1, hv[(size_t)csr_pad[e0 + j] * 32 + lane]);
    }

    float4 s = f4add(f4add(a0, a1), f4add(a2, a3));
    const float dv = rsqrtf((float)(deg + 1));
    const float4 bb = ((const float4*)bias)[lane];
    float4 o;
    o.x = fmaxf(fmaf(s.x, dv, bb.x), 0.f);
    o.y = fmaxf(fmaf(s.y, dv, bb.y), 0.f);
    o.z = fmaxf(fmaf(s.z, dv, bb.z), 0.f);
    o.w = fmaxf(fmaf(s.w, dv, bb.w), 0.f);
    ((float4*)hout)[(size_t)node * 32 + lane] = o;

    if (scores) {  // wave-uniform branch (fused pooling score)
        float4 pv = ((const float4*)pool_p)[lane];
        float d  = o.x * pv.x + o.y * pv.y + o.z * pv.z + o.w * pv.w;
        float nn = pv.x * pv.x + pv.y * pv.y + pv.z * pv.z + pv.w * pv.w;
#pragma unroll
        for (int off = 16; off > 0; off >>= 1) {
            d  += __shfl_xor(d, off);
            nn += __shfl_xor(nn, off);
        }
        if (lane == 0) scores[node] = d * rsqrtf(nn);
    }
}

// ==================== TopK pool (k=256 of 512) + MLP head ===================
__global__ __launch_bounds__(512) void topk_mlp(
    const float* __restrict__ scores, const float* __restrict__ h,
    const float* __restrict__ fc1W, const float* __restrict__ fc1b,
    const float* __restrict__ fc2W, const float* __restrict__ fc2b,
    const float* __restrict__ fc3W, const float* __restrict__ fc3b,
    float* __restrict__ out)
{
    __shared__ float s[512];
    __shared__ int   sel[256];
    __shared__ float w[256];
    __shared__ float4 red[512];
    __shared__ float pld[128];
    __shared__ float z1[128];
    __shared__ float z2[64];
    const int g = blockIdx.x;
    const int i = threadIdx.x;
    s[i] = scores[g * 512 + i];
    __syncthreads();
    float si = s[i];
    int rank = 0;
    for (int j = 0; j < 512; j++) {
        float sj = s[j];
        rank += (sj > si) || (sj == si && j < i);
    }
    if (rank < 256) {
        sel[rank] = i;
        w[rank]   = tanhf(si) * (1.f / 256.f);
    }
    __syncthreads();
    const int c   = (i & 31) * 4;
    const int grp = i >> 5;
    float4 acc = make_float4(0.f, 0.f, 0.f, 0.f);
    for (int t = grp; t < 256; t += 16) {
        float wt  = w[t];
        int   idx = sel[t];
        float4 r = *(const float4*)&h[((size_t)g * 512 + idx) * 128 + c];
        acc = f4fma(wt, r, acc);
    }
    red[i] = acc;
    __syncthreads();
    if (i < 256) red[i] = f4add(red[i], red[i + 256]);
    __syncthreads();
    if (i < 128) red[i] = f4add(red[i], red[i + 128]);
    __syncthreads();
    if (i < 64) red[i] = f4add(red[i], red[i + 64]);
    __syncthreads();
    if (i < 32) {
        float4 v = f4add(red[i], red[i + 32]);
        *(float4*)&pld[i * 4] = v;
    }
    __syncthreads();
    if (i < 128) {
        float a = fc1b[i];
        for (int k = 0; k < 128; k++) a += pld[k] * fc1W[k * 128 + i];
        z1[i] = fmaxf(a, 0.f);
    }
    __syncthreads();
    if (i < 64) {
        float b = fc2b[i];
        for (int k = 0; k < 128; k++) b += z1[k] * fc2W[k * 64 + i];
        z2[i] = fmaxf(b, 0.f);
    }
    __syncthreads();
    if (i < 10) {
        float o = fc3b[i];
        for (int k = 0; k < 64; k++) o += z2[k] * fc3W[k * 10 + i];
        out[g * 10 + i] = o;
    }
}

// ============================ Launcher ======================================
extern "C" void kernel_launch(void* const* d_in, const int* in_sizes, int n_in,
                              void* d_out, int out_size, void* d_ws, size_t ws_size,
                              hipStream_t stream)
{
    const float* x     = (const float*)d_in[0];
    const int*   eidx  = (const int*)d_in[1];
    const float* embW  = (const float*)d_in[3];
    const float* embb  = (const float*)d_in[4];
    const float* gcnW  = (const float*)d_in[5];
    const float* gcnb  = (const float*)d_in[6];
    const float* poolp = (const float*)d_in[7];
    const float* fc1W  = (const float*)d_in[8];
    const float* fc1b  = (const float*)d_in[9];
    const float* fc2W  = (const float*)d_in[10];
    const float* fc2b  = (const float*)d_in[11];
    const float* fc3W  = (const float*)d_in[12];
    const float* fc3b  = (const float*)d_in[13];
    float* out = (float*)d_out;

    const int n = in_sizes[0] / 128;   // 65536
    const int E = in_sizes[1] / 2;     // 524288
    const int G = n / 512;             // 128

    const int* src = eidx;
    const int* dst = eidx + E;

    char* ws = (char*)d_ws;
    size_t off = 0;
    auto carve = [&](size_t bytes) {
        void* p = ws + off;
        off += (bytes + 255) & ~(size_t)255;
        return p;
    };
    float* h       = (float*)carve((size_t)n * 128 * 4);
    float* hsA     = (float*)carve((size_t)(n + 1) * 128 * 4);  // +zero row
    float* hsB     = (float*)carve((size_t)(n + 1) * 128 * 4);  // +zero row
    int*   cnt     = (int*)carve((size_t)n * 4);
    int*   csr_pad = (int*)carve((size_t)n * SLOTS * 4);
    float* scores  = (float*)carve((size_t)n * 4);
    float* W01     = (float*)carve(128 * 128 * 4);
    float* b01     = (float*)carve(128 * 4);
    (void)ws_size;

    const int EB = E / 256;            // 2048 edge blocks

    // ---- zero degree counters, then fused CSR build + weight fold ----
    hipMemsetAsync(cnt, 0, (size_t)n * 4, stream);
    build_graph_fold<<<EB + 129, 256, 0, stream>>>(
        src, dst, cnt, csr_pad, E, EB, embW, embb, gcnW, W01, b01,
        hsA + (size_t)n * 128, hsB + (size_t)n * 128);

    // ---- layer 0 GEMM (folded embedding) -> hsA ----
    gemm128<<<n / 128, 256, 0, stream>>>(x, W01, b01, cnt, hsA, n);

    // ---- fused agg0+gemm1 (hsA->hsB), agg1+gemm2 (hsB->hsA) ----
    agg_gemm<<<n / 128, 256, 0, stream>>>(hsA, csr_pad, cnt, gcnb,
                                          gcnW + (size_t)1 * 128 * 128, hsB, n);
    agg_gemm<<<n / 128, 256, 0, stream>>>(hsB, csr_pad, cnt, gcnb + 128,
                                          gcnW + (size_t)2 * 128 * 128, hsA, n);

    // ---- last aggregate (h + fused pooling scores) ----
    aggregate<<<n / 8, 256, 0, stream>>>(hsA, csr_pad, cnt, gcnb + 256, h,
                                         poolp, scores, n);

    // ---- fused topk pool + MLP ----
    topk_mlp<<<G, 512, 0, stream>>>(scores, h, fc1W, fc1b, fc2W, fc2b,
                                    fc3W, fc3b, out);
}